// Round 15
// baseline (684.808 us; speedup 1.0000x reference)
//
#include <hip/hip_runtime.h>
#include <hip/hip_bf16.h>
#include <cstdint>
#include <cstddef>

#define DIM_ 2048
#define HV_ 32
#define HK_ 16
#define DK_ 128
#define DV_ 128
#define KW_ 4
#define KEY_DIM_ 2048
#define VAL_DIM_ 4096
#define CONV_DIM_ 8192
#define B_ 2
#define T_ 2048
#define BT_ 4096
#define CH_ 64
#define NC_ (T_ / CH_)

typedef short s8v __attribute__((ext_vector_type(8)));
typedef float f4v __attribute__((ext_vector_type(4)));

__device__ __forceinline__ unsigned short f2b(float f) {
    union { float f; unsigned u; } c; c.f = f;
    unsigned u = c.u;
    return (unsigned short)((u + 0x7fffu + ((u >> 16) & 1u)) >> 16);
}
__device__ __forceinline__ float b2f(unsigned short s) {
    union { unsigned u; float f; } c; c.u = ((unsigned)s) << 16;
    return c.f;
}
__device__ __forceinline__ unsigned int pk2(float a, float b) {
    return (unsigned)f2b(a) | ((unsigned)f2b(b) << 16);
}
__device__ __forceinline__ float silu(float x) { return x / (1.f + expf(-x)); }

// ---------------- cast f32 -> bf16 ----------------
__global__ void cast_bf16_k(const float* __restrict__ in, unsigned short* __restrict__ out, int n8) {
    int i = blockIdx.x * blockDim.x + threadIdx.x;
    if (i >= n8) return;
    int base = i * 8;
    f4v a = *(const f4v*)(in + base);
    f4v b = *(const f4v*)(in + base + 4);
    s8v o;
    o[0] = (short)f2b(a[0]); o[1] = (short)f2b(a[1]); o[2] = (short)f2b(a[2]); o[3] = (short)f2b(a[3]);
    o[4] = (short)f2b(b[0]); o[5] = (short)f2b(b[1]); o[6] = (short)f2b(b[2]); o[7] = (short)f2b(b[3]);
    *(s8v*)(out + base) = o;
}

// ---------------- transpose + cast ----------------
__global__ void transpose_cast_k(const float* __restrict__ in, unsigned short* __restrict__ out,
                                 int R, int C) {
    __shared__ float tile[32][33];
    int c0 = blockIdx.x * 32, r0 = blockIdx.y * 32;
    int tx = threadIdx.x & 31, ty = threadIdx.x >> 5;
#pragma unroll
    for (int j = 0; j < 32; j += 8)
        tile[ty + j][tx] = in[(size_t)(r0 + ty + j) * C + c0 + tx];
    __syncthreads();
#pragma unroll
    for (int j = 0; j < 32; j += 8)
        out[(size_t)(c0 + ty + j) * R + r0 + tx] = f2b(tile[tx][ty + j]);
}

// ---------------- pack W_a||W_b -> WabP[512][64][4] f32 ----------------
__global__ void pack_ab_k(const float* __restrict__ Wa, const float* __restrict__ Wb,
                          float* __restrict__ WabP) {
    int idx = blockIdx.x * 256 + threadIdx.x;
    int k = idx >> 6;
    int c = idx & 63;
    float v = (c < 32) ? Wa[(size_t)k * 32 + c] : Wb[(size_t)k * 32 + (c - 32)];
    WabP[((size_t)(k >> 2) * 64 + c) * 4 + (k & 3)] = v;
}

// ================ 256x256 8-phase bf16 GEMM (m201 template, plain HIP) ================
template <int OUT_BF16>
__global__ __launch_bounds__(512) void gemm256_bt_k(const unsigned short* __restrict__ A,
                                                    const unsigned short* __restrict__ BT,
                                                    void* __restrict__ Cv,
                                                    int M, int N, int K) {
    extern __shared__ char lds[];   // 131072 B
    const int tid = threadIdx.x;
    const int wid = tid >> 6, lane = tid & 63;
    const int wm = wid >> 2, wn = wid & 3;
    const int r15 = lane & 15, g4 = lane >> 4;
    const int m0 = blockIdx.y * 256, n0 = blockIdx.x * 256;
    const int NT = K >> 6;

    f4v acc[8][4];
#pragma unroll
    for (int i = 0; i < 8; i++)
#pragma unroll
        for (int j = 0; j < 4; j++) acc[i][j] = (f4v){0.f, 0.f, 0.f, 0.f};

    const int i8 = lane >> 3;
    const int colb = (lane & 7) << 4;

    auto stage = [&](int unit, int t) {
        int buf = t & 1;
        int matB = (unit == 1 || unit == 2);
        int rs0;
        if (unit == 0)      rs0 = wid * 8;
        else if (unit == 3) rs0 = 64 + wid * 8;
        else                rs0 = (wid < 4 ? wid * 8 : 64 + (wid - 4) * 8) + (unit == 2 ? 32 : 0);
#pragma unroll
        for (int p = 0; p < 2; p++) {
            int rowst = rs0 + p * 128;
            int row = rowst + i8;
            int scol = colb ^ ((row & 7) << 4);
            const unsigned short* g = (matB ? BT + (size_t)(n0 + row) * K
                                            : A  + (size_t)(m0 + row) * K)
                                      + t * 64 + (scol >> 1);
            char* l = lds + buf * 65536 + matB * 32768 + rowst * 128;
            __builtin_amdgcn_global_load_lds(
                (const __attribute__((address_space(1))) unsigned int*)g,
                (__attribute__((address_space(3))) unsigned int*)l, 16, 0, 0);
        }
    };
    auto loadA = [&](s8v* af, int mh, int buf) {
        char* base = lds + buf * 65536;
#pragma unroll
        for (int mi = 0; mi < 4; mi++) {
            int row = wm * 128 + mh * 64 + mi * 16 + r15;
#pragma unroll
            for (int kk = 0; kk < 2; kk++) {
                int off = row * 128 + ((kk * 64 + g4 * 16) ^ ((row & 7) << 4));
                af[mi * 2 + kk] = *(const s8v*)(base + off);
            }
        }
    };
    auto loadB = [&](s8v* bf, int nh, int buf) {
        char* base = lds + buf * 65536 + 32768;
#pragma unroll
        for (int ni = 0; ni < 2; ni++) {
            int row = wn * 64 + nh * 32 + ni * 16 + r15;
#pragma unroll
            for (int kk = 0; kk < 2; kk++) {
                int off = row * 128 + ((kk * 64 + g4 * 16) ^ ((row & 7) << 4));
                bf[ni * 2 + kk] = *(const s8v*)(base + off);
            }
        }
    };
    auto mfma16 = [&](s8v* af, s8v* bf, int mh, int nh) {
#pragma unroll
        for (int mi = 0; mi < 4; mi++)
#pragma unroll
            for (int ni = 0; ni < 2; ni++)
#pragma unroll
                for (int kk = 0; kk < 2; kk++)
                    acc[mh * 4 + mi][nh * 2 + ni] = __builtin_amdgcn_mfma_f32_16x16x32_bf16(
                        af[mi * 2 + kk], bf[ni * 2 + kk], acc[mh * 4 + mi][nh * 2 + ni], 0, 0, 0);
    };

    stage(0, 0); stage(1, 0); stage(2, 0); stage(3, 0);
    stage(0, 1); stage(1, 1); stage(2, 1);
    asm volatile("s_waitcnt vmcnt(6)" ::: "memory");
    __builtin_amdgcn_s_barrier();

    for (int u = 0; u < NT; u++) {
        int buf = u & 1;
        s8v afE[8], afO[8], bfE[4], bfO[4];

        loadA(afE, 0, buf); loadB(bfE, 0, buf);
        if (u + 1 < NT) stage(3, u + 1);
        __builtin_amdgcn_s_barrier();
        asm volatile("s_waitcnt lgkmcnt(0)" ::: "memory");
        __builtin_amdgcn_sched_barrier(0);
        __builtin_amdgcn_s_setprio(1);
        mfma16(afE, bfE, 0, 0);
        __builtin_amdgcn_s_setprio(0);
        __builtin_amdgcn_s_barrier();

        loadB(bfO, 1, buf);
        if (u + 2 < NT) stage(0, u + 2);
        __builtin_amdgcn_s_barrier();
        asm volatile("s_waitcnt lgkmcnt(0)" ::: "memory");
        __builtin_amdgcn_sched_barrier(0);
        __builtin_amdgcn_s_setprio(1);
        mfma16(afE, bfO, 0, 1);
        __builtin_amdgcn_s_setprio(0);
        __builtin_amdgcn_s_barrier();

        loadA(afO, 1, buf);
        if (u + 2 < NT) stage(1, u + 2);
        __builtin_amdgcn_s_barrier();
        asm volatile("s_waitcnt lgkmcnt(0)" ::: "memory");
        __builtin_amdgcn_sched_barrier(0);
        __builtin_amdgcn_s_setprio(1);
        mfma16(afO, bfO, 1, 1);
        __builtin_amdgcn_s_setprio(0);
        __builtin_amdgcn_s_barrier();

        if (u + 2 < NT) stage(2, u + 2);
        __builtin_amdgcn_s_barrier();
        __builtin_amdgcn_s_setprio(1);
        mfma16(afO, bfE, 1, 0);
        __builtin_amdgcn_s_setprio(0);
        if (u == NT - 2) asm volatile("s_waitcnt vmcnt(0)" ::: "memory");
        else             asm volatile("s_waitcnt vmcnt(6)" ::: "memory");
        __builtin_amdgcn_s_barrier();
    }

#pragma unroll
    for (int mi = 0; mi < 8; mi++)
#pragma unroll
        for (int ni = 0; ni < 4; ni++) {
            int row = m0 + wm * 128 + mi * 16 + g4 * 4;
            int col = n0 + wn * 64 + ni * 16 + r15;
#pragma unroll
            for (int r = 0; r < 4; r++) {
                float v = acc[mi][ni][r];
                if (OUT_BF16)
                    ((unsigned short*)Cv)[(size_t)(row + r) * N + col] = f2b(v);
                else
                    ((float*)Cv)[(size_t)(row + r) * N + col] = v;
            }
        }
}

// ---------------- a,b GEMM (exact f32) + g/beta ----------------
__global__ __launch_bounds__(256) void ab_gbeta_k(const float* __restrict__ x,
                                                  const float* __restrict__ WabP,
                                                  const float* __restrict__ dt_bias,
                                                  const float* __restrict__ A_log,
                                                  float* __restrict__ g, float* __restrict__ beta) {
    const int c = threadIdx.x & 63;
    const int rg = __builtin_amdgcn_readfirstlane(threadIdx.x >> 6);
    const int row = blockIdx.x * 4 + rg;
    const float* xp = x + (size_t)row * 2048;
    const float* wp = WabP + c * 4;
    float acc0 = 0.f, acc1 = 0.f;
#pragma unroll 4
    for (int kb = 0; kb < 512; kb += 2) {
        f4v w0 = *(const f4v*)(wp + (size_t)kb * 256);
        f4v w1 = *(const f4v*)(wp + (size_t)(kb + 1) * 256);
        f4v x0 = *(const f4v*)(xp + kb * 4);
        f4v x1 = *(const f4v*)(xp + kb * 4 + 4);
        acc0 += x0[0] * w0[0] + x0[1] * w0[1] + x0[2] * w0[2] + x0[3] * w0[3];
        acc1 += x1[0] * w1[0] + x1[1] * w1[1] + x1[2] * w1[2] + x1[3] * w1[3];
    }
    float tot = acc0 + acc1;
    if (c < 32) {
        float av = tot + dt_bias[c];
        float sp = (av > 20.f) ? av : log1pf(expf(av));
        g[(size_t)row * 32 + c] = -expf(A_log[c]) * sp;
    } else {
        beta[(size_t)row * 32 + (c - 32)] = 1.f / (1.f + expf(-tot));
    }
}

// ---------------- conv + silu + l2norm + split (1 t/thread) ----------------
__global__ __launch_bounds__(256) void conv_fused_k(const unsigned short* __restrict__ mixp,
                                                    const float* __restrict__ convw,
                                                    unsigned short* __restrict__ qn,
                                                    unsigned short* __restrict__ kn,
                                                    unsigned short* __restrict__ vv) {
    int btid = blockIdx.x;
    int t = btid & (T_ - 1);
    int c = (blockIdx.y << 9) + (threadIdx.x << 1);
    const unsigned short* base = mixp + (size_t)btid * CONV_DIM_ + c;
    unsigned m3 = *(const unsigned*)(base);
    unsigned m2 = (t >= 1) ? *(const unsigned*)(base - CONV_DIM_) : 0u;
    unsigned m1 = (t >= 2) ? *(const unsigned*)(base - 2 * CONV_DIM_) : 0u;
    unsigned m0 = (t >= 3) ? *(const unsigned*)(base - 3 * CONV_DIM_) : 0u;
    f4v w0 = *(const f4v*)(convw + (size_t)c * 4);
    f4v w1 = *(const f4v*)(convw + (size_t)c * 4 + 4);
    float v0 = b2f((unsigned short)(m3 & 0xffff)) * w0[3] + b2f((unsigned short)(m2 & 0xffff)) * w0[2]
             + b2f((unsigned short)(m1 & 0xffff)) * w0[1] + b2f((unsigned short)(m0 & 0xffff)) * w0[0];
    float v1 = b2f((unsigned short)(m3 >> 16)) * w1[3] + b2f((unsigned short)(m2 >> 16)) * w1[2]
             + b2f((unsigned short)(m1 >> 16)) * w1[1] + b2f((unsigned short)(m0 >> 16)) * w1[0];
    v0 = silu(v0); v1 = silu(v1);
    if (c < 2 * KEY_DIM_) {
        float ss = v0 * v0 + v1 * v1;
#pragma unroll
        for (int m = 1; m < 64; m <<= 1) ss += __shfl_xor(ss, m);
        float scale = rsqrtf(ss + 1e-6f);
        int head = (c >> 7) & 15, d = c & 127;
        if (c < KEY_DIM_) {
            scale *= 0.08838834764831845f;
            *(unsigned*)(qn + ((size_t)btid * HK_ + head) * DK_ + d) = pk2(v0 * scale, v1 * scale);
        } else {
            *(unsigned*)(kn + ((size_t)btid * HK_ + head) * DK_ + d) = pk2(v0 * scale, v1 * scale);
        }
    } else {
        *(unsigned*)(vv + (size_t)btid * VAL_DIM_ + (c - 2 * KEY_DIM_)) = pk2(v0, v1);
    }
}

// ================= chunked delta rule: parallel precompute (h-pair merged) =================
// R15: AT pad 68->65 floats. R14's STmp3 (+2176B) crossed the 3-blocks/CU LDS
// boundary (3x54976 > 160KB) -> 2 blocks/CU -> +30us. New total 54208B -> 3/CU,
// keeping the per-I trisolve barrier reduction. Stride 65 = bank-stride 1 (good).
__global__ __launch_bounds__(256) void chunk_pre_k(
    const unsigned short* __restrict__ qn, const unsigned short* __restrict__ kn,
    unsigned short* __restrict__ vv,
    const float* __restrict__ g, const float* __restrict__ beta,
    unsigned short* __restrict__ Wg, unsigned short* __restrict__ Aog,
    unsigned short* __restrict__ knT, float* __restrict__ expG, float* __restrict__ expGr)
{
    const int c = blockIdx.x, hp = blockIdx.y, b = blockIdx.z;
    const int tid = threadIdx.x, wid = tid >> 6, lane = tid & 63;
    const int r15 = lane & 15, g4 = lane >> 4;

    __shared__ __attribute__((aligned(16))) unsigned short Klds[64 * 128];
    __shared__ __attribute__((aligned(16))) unsigned short Xlds[128 * 64];
    __shared__ float AT[64][65];
    __shared__ float STmp3[3][16][17];
    __shared__ float Gl2[2][64], Bl2[2][64], EG2[2][64];

    const size_t t0 = (size_t)b * T_ + (size_t)c * 64;

#pragma unroll
    for (int p = 0; p < 4; p++) {
        int row = p * 16 + (tid >> 4);
        int colB = (tid & 15) << 4;
        int sw = colB ^ ((row & 7) << 4);
        s8v kv = *(const s8v*)(kn + ((t0 + row) * HK_ + hp) * DK_ + (colB >> 1));
        *(s8v*)((char*)Klds + row * 256 + sw) = kv;
        s8v qv = *(const s8v*)(qn + ((t0 + row) * HK_ + hp) * DK_ + (colB >> 1));
        *(s8v*)((char*)Xlds + row * 256 + sw) = qv;
    }
    if (wid < 2) {
        int h = hp * 2 + wid;
        float v = g[(t0 + lane) * HV_ + h];
        float bv = beta[(t0 + lane) * HV_ + h];
#pragma unroll
        for (int off = 1; off < 64; off <<= 1) {
            float n = __shfl_up(v, off);
            if (lane >= off) v += n;
        }
        float Gn = __shfl(v, 63);
        float e1 = expf(v), e2 = expf(Gn - v);
        Gl2[wid][lane] = v;
        Bl2[wid][lane] = bv;
        EG2[wid][lane] = e1;
        size_t cbk = ((size_t)(b * 32 + h) * 32 + c);
        expG[cbk * 64 + lane] = e1;
        expGr[cbk * 64 + lane] = e2;
    }
    __syncthreads();

    f4v kkv[4], qkv[4];
#pragma unroll
    for (int jt = 0; jt < 4; jt++) { kkv[jt] = (f4v){0,0,0,0}; qkv[jt] = (f4v){0,0,0,0}; }
    const int arow = wid * 16 + r15;
#pragma unroll
    for (int ks = 0; ks < 4; ks++) {
        int abyte = arow * 256 + ((ks * 64 + (g4 << 4)) ^ ((arow & 7) << 4));
        s8v ak = *(const s8v*)((const char*)Klds + abyte);
        s8v aq = *(const s8v*)((const char*)Xlds + abyte);
#pragma unroll
        for (int jt = 0; jt < 4; jt++) {
            int jrow = jt * 16 + r15;
            int bbyte = jrow * 256 + ((ks * 64 + (g4 << 4)) ^ ((jrow & 7) << 4));
            s8v bk = *(const s8v*)((const char*)Klds + bbyte);
            kkv[jt] = __builtin_amdgcn_mfma_f32_16x16x32_bf16(ak, bk, kkv[jt], 0, 0, 0);
            qkv[jt] = __builtin_amdgcn_mfma_f32_16x16x32_bf16(aq, bk, qkv[jt], 0, 0, 0);
        }
    }

    for (int hh = 0; hh < 2; hh++) {
        const int h = hp * 2 + hh;
        const size_t cbk = ((size_t)(b * 32 + h) * 32 + c);

#pragma unroll
        for (int jt = 0; jt < 4; jt++) {
#pragma unroll
            for (int r = 0; r < 4; r++) {
                int i = wid * 16 + g4 * 4 + r;
                int j = jt * 16 + r15;
                float em = expf(fminf(Gl2[hh][i] - Gl2[hh][j], 0.f));
                AT[i][j] = (j < i) ? Bl2[hh][i] * em * kkv[jt][r] : 0.f;
                float ao = (j <= i) ? em * qkv[jt][r] : 0.f;
                Aog[cbk * 4096 + i * 64 + j] = f2b(ao);
            }
        }
        __syncthreads();

        for (int u = tid; u < 1024; u += 256) {
            int row = u >> 4, v0i = (u & 15) << 3;
            s8v vx = *(const s8v*)(vv + (t0 + row) * VAL_DIM_ + h * 128 + v0i);
            float bt = Bl2[hh][row];
#pragma unroll
            for (int e = 0; e < 8; e++) {
                int v = v0i + e;
                *(unsigned short*)((char*)Xlds + v * 128 + ((row * 2) ^ ((v & 7) << 4))) =
                    f2b(b2f((unsigned short)vx[e]) * bt);
            }
        }
        if (hh == 0) {
            int dk = tid & 127, th = (tid >> 7) << 5;
            size_t basek = ((size_t)(b * 16 + hp) * 128 + dk) * (size_t)T_ + (size_t)c * 64 + th;
#pragma unroll
            for (int t8 = 0; t8 < 4; t8++) {
                s8v kv;
#pragma unroll
                for (int e = 0; e < 8; e++) {
                    int tt = th + t8 * 8 + e;
                    kv[e] = (short)*(const unsigned short*)((const char*)Klds + tt * 256 + ((dk * 2) ^ ((tt & 7) << 4)));
                }
                *(s8v*)(knT + basek + t8 * 8) = kv;
            }
        }
        __syncthreads();

        if (lane < 16) {
            int r0 = wid * 16, col = lane;
#pragma unroll
            for (int i = 0; i < 16; i++) {
                float s = 0.f;
                for (int j = 0; j < i; j++) s += AT[r0 + i][r0 + j] * AT[r0 + j][r0 + col];
                AT[r0 + i][r0 + col] = ((col == i) ? 1.f : 0.f) - s;
            }
        }
        __syncthreads();

        // c3: per-I, all J in parallel (2 barriers per I)
        {
            int ii = tid >> 4, jj = tid & 15;
            for (int I = 1; I < 4; I++) {
                for (int J = 0; J < I; J++) {
                    float s = 0.f;
                    for (int K = J; K < I; K++)
#pragma unroll
                        for (int m = 0; m < 16; m++)
                            s += AT[16 * I + ii][16 * K + m] * AT[16 * K + m][16 * J + jj];
                    STmp3[J][ii][jj] = s;
                }
                __syncthreads();
                for (int J = 0; J < I; J++) {
                    float y = 0.f;
#pragma unroll
                    for (int m = 0; m < 16; m++) y += AT[16 * I + ii][16 * I + m] * STmp3[J][m][jj];
                    AT[16 * I + ii][16 * J + jj] = -y;
                }
                __syncthreads();
            }
        }

        f4v tb[8];
#pragma unroll
        for (int vt = 0; vt < 8; vt++) tb[vt] = (f4v){0,0,0,0};
#pragma unroll
        for (int ks = 0; ks < 2; ks++) {
            s8v ta;
#pragma unroll
            for (int e = 0; e < 8; e++) ta[e] = (short)f2b(AT[arow][ks * 32 + g4 * 8 + e]);
#pragma unroll
            for (int vt = 0; vt < 8; vt++) {
                int v = vt * 16 + r15;
                int bbyte = v * 128 + ((ks * 64 + (g4 << 4)) ^ ((v & 7) << 4));
                s8v bv = *(const s8v*)((const char*)Xlds + bbyte);
                tb[vt] = __builtin_amdgcn_mfma_f32_16x16x32_bf16(ta, bv, tb[vt], 0, 0, 0);
            }
        }
#pragma unroll
        for (int vt = 0; vt < 8; vt++)
#pragma unroll
            for (int r = 0; r < 4; r++) {
                int i = wid * 16 + g4 * 4 + r, v = vt * 16 + r15;
                vv[(t0 + i) * VAL_DIM_ + h * 128 + v] = f2b(tb[vt][r]);
            }
        __syncthreads();

        {
            int dk = tid & 127;
            int tb0 = (tid >> 7) << 5;
#pragma unroll
            for (int t8 = 0; t8 < 4; t8++) {
                int tbase = tb0 + t8 * 8;
                s8v kw;
#pragma unroll
                for (int e = 0; e < 8; e++) {
                    int t = tbase + e;
                    float kv = b2f(*(const unsigned short*)((const char*)Klds + t * 256 + ((dk * 2) ^ ((t & 7) << 4))));
                    kw[e] = (short)f2b(kv * Bl2[hh][t] * EG2[hh][t]);
                }
                *(s8v*)((char*)Xlds + dk * 128 + ((tbase * 2) ^ ((dk & 7) << 4))) = kw;
            }
        }
        __syncthreads();

        f4v wm[8];
#pragma unroll
        for (int dt = 0; dt < 8; dt++) wm[dt] = (f4v){0,0,0,0};
#pragma unroll
        for (int ks = 0; ks < 2; ks++) {
            s8v ta;
#pragma unroll
            for (int e = 0; e < 8; e++) ta[e] = (short)f2b(AT[arow][ks * 32 + g4 * 8 + e]);
#pragma unroll
            for (int dt = 0; dt < 8; dt++) {
                int dkr = dt * 16 + r15;
                int bbyte = dkr * 128 + ((ks * 64 + (g4 << 4)) ^ ((dkr & 7) << 4));
                s8v bw = *(const s8v*)((const char*)Xlds + bbyte);
                wm[dt] = __builtin_amdgcn_mfma_f32_16x16x32_bf16(ta, bw, wm[dt], 0, 0, 0);
            }
        }
#pragma unroll
        for (int dt = 0; dt < 8; dt++)
#pragma unroll
            for (int r = 0; r < 4; r++) {
                int i = wid * 16 + g4 * 4 + r, dk = dt * 16 + r15;
                Wg[cbk * 8192 + i * 128 + dk] = f2b(wm[dt][r]);
            }
        __syncthreads();
    }
}

// ================= chunked delta rule: sequential scan =================
__global__ __launch_bounds__(256) void chunk_scan_k(
    const unsigned short* __restrict__ qn, const unsigned short* __restrict__ knT,
    const unsigned short* __restrict__ tbv,
    const unsigned short* __restrict__ Wg, const unsigned short* __restrict__ Aog,
    const float* __restrict__ expG, const float* __restrict__ expGr,
    unsigned short* __restrict__ ob)
{
    const int bx = blockIdx.x;
    const int vq = bx & 3, h = (bx >> 2) & 31, b = bx >> 7;
    const int hk = h >> 1;
    const int tid = threadIdx.x, wid = tid >> 6, lane = tid & 63;
    const int r15 = lane & 15, g4 = lane >> 4;

    __shared__ __attribute__((aligned(16))) unsigned short Slds[32 * 128];
    __shared__ __attribute__((aligned(16))) unsigned short Ulds[32 * 64];
    __shared__ __attribute__((aligned(16))) unsigned short Uplds[32 * 64];

    f4v S[2][2];
#pragma unroll
    for (int i = 0; i < 2; i++)
#pragma unroll
        for (int j = 0; j < 2; j++) S[i][j] = (f4v){0,0,0,0};

    struct ScanOps {
        s8v aw[4], aa[2], ak[4], q0[4];
        float tv[8], egr4[4], egi, gam;
    };
    ScanOps opA, opB;

    const unsigned short* kpbase = knT + ((size_t)(b * 16 + hk) * 128) * (size_t)T_;

    auto scan_load = [&](ScanOps& o, int c) {
        const size_t cbk = ((size_t)(b * 32 + h) * 32 + c);
        const size_t t0 = (size_t)b * T_ + (size_t)c * 64;
        const unsigned short* wp = Wg + cbk * 8192 + (size_t)(wid * 16 + r15) * 128;
#pragma unroll
        for (int ks = 0; ks < 4; ks++) o.aw[ks] = *(const s8v*)(wp + ks * 32 + g4 * 8);
        const unsigned short* ap = Aog + cbk * 4096 + (size_t)(wid * 16 + r15) * 64;
#pragma unroll
        for (int ks = 0; ks < 2; ks++) o.aa[ks] = *(const s8v*)(ap + ks * 32 + g4 * 8);
#pragma unroll
        for (int ks = 0; ks < 2; ks++)
#pragma unroll
            for (int dkt = 0; dkt < 2; dkt++)
                o.ak[ks * 2 + dkt] = *(const s8v*)(kpbase +
                    (size_t)((wid * 2 + dkt) * 16 + r15) * T_ + (size_t)c * 64 + ks * 32 + g4 * 8);
        const unsigned short* qp = qn + ((t0 + wid * 16 + r15) * HK_ + hk) * DK_;
#pragma unroll
        for (int ks = 0; ks < 4; ks++) o.q0[ks] = *(const s8v*)(qp + ks * 32 + g4 * 8);
#pragma unroll
        for (int vt = 0; vt < 2; vt++)
#pragma unroll
            for (int r = 0; r < 4; r++) {
                int t = wid * 16 + g4 * 4 + r;
                o.tv[vt * 4 + r] = b2f(tbv[(t0 + t) * VAL_DIM_ + h * 128 + vq * 32 + vt * 16 + r15]);
            }
#pragma unroll
        for (int r = 0; r < 4; r++) o.egr4[r] = expGr[cbk * 64 + wid * 16 + g4 * 4 + r];
        o.egi = expG[cbk * 64 + wid * 16 + r15];
        o.gam = expG[cbk * 64 + 63];
    };

    auto body = [&](ScanOps& o, int c) {
#pragma unroll
        for (int dkt = 0; dkt < 2; dkt++)
#pragma unroll
            for (int vt = 0; vt < 2; vt++) {
                int v = vt * 16 + r15;
                int dkb = ((wid * 2 + dkt) * 16 + g4 * 4) * 2;
                int sw = (v & 7) << 4;
                *(unsigned int*)((char*)Slds + v * 256 + ((dkb) ^ sw))     = pk2(S[dkt][vt][0], S[dkt][vt][1]);
                *(unsigned int*)((char*)Slds + v * 256 + ((dkb + 4) ^ sw)) = pk2(S[dkt][vt][2], S[dkt][vt][3]);
            }
        __syncthreads();

        f4v P[2]; P[0] = (f4v){0,0,0,0}; P[1] = (f4v){0,0,0,0};
        s8v sf[4][2];
#pragma unroll
        for (int ks = 0; ks < 4; ks++)
#pragma unroll
            for (int vt = 0; vt < 2; vt++) {
                int v = vt * 16 + r15;
                sf[ks][vt] = *(const s8v*)((const char*)Slds + v * 256 + ((ks * 64 + g4 * 16) ^ ((v & 7) << 4)));
                P[vt] = __builtin_amdgcn_mfma_f32_16x16x32_bf16(o.aw[ks], sf[ks][vt], P[vt], 0, 0, 0);
            }
#pragma unroll
        for (int vt = 0; vt < 2; vt++) {
            float uu[4], up[4];
#pragma unroll
            for (int r = 0; r < 4; r++) {
                uu[r] = o.tv[vt * 4 + r] - P[vt][r];
                up[r] = uu[r] * o.egr4[r];
            }
            int v = vt * 16 + r15;
            int tb2 = (wid * 16 + g4 * 4) * 2;
            int sw = (v & 7) << 4;
            *(unsigned int*)((char*)Ulds  + v * 128 + ((tb2) ^ sw))     = pk2(uu[0], uu[1]);
            *(unsigned int*)((char*)Ulds  + v * 128 + ((tb2 + 4) ^ sw)) = pk2(uu[2], uu[3]);
            *(unsigned int*)((char*)Uplds + v * 128 + ((tb2) ^ sw))     = pk2(up[0], up[1]);
            *(unsigned int*)((char*)Uplds + v * 128 + ((tb2 + 4) ^ sw)) = pk2(up[2], up[3]);
        }

        f4v O[2]; O[0] = (f4v){0,0,0,0}; O[1] = (f4v){0,0,0,0};
#pragma unroll
        for (int ks = 0; ks < 4; ks++) {
            s8v qg;
#pragma unroll
            for (int e = 0; e < 8; e++) qg[e] = (short)f2b(b2f((unsigned short)o.q0[ks][e]) * o.egi);
#pragma unroll
            for (int vt = 0; vt < 2; vt++)
                O[vt] = __builtin_amdgcn_mfma_f32_16x16x32_bf16(qg, sf[ks][vt], O[vt], 0, 0, 0);
        }
        __syncthreads();

#pragma unroll
        for (int ks = 0; ks < 2; ks++)
#pragma unroll
            for (int vt = 0; vt < 2; vt++) {
                int v = vt * 16 + r15;
                s8v bu = *(const s8v*)((const char*)Ulds + v * 128 + ((ks * 64 + g4 * 16) ^ ((v & 7) << 4)));
                O[vt] = __builtin_amdgcn_mfma_f32_16x16x32_bf16(o.aa[ks], bu, O[vt], 0, 0, 0);
            }
#pragma unroll
        for (int vt = 0; vt < 2; vt++)
#pragma unroll
            for (int r = 0; r < 4; r++) {
                int t = c * 64 + wid * 16 + g4 * 4 + r;
                ob[((size_t)b * T_ + t) * VAL_DIM_ + h * 128 + vq * 32 + vt * 16 + r15] = f2b(O[vt][r]);
            }

#pragma unroll
        for (int dkt = 0; dkt < 2; dkt++)
#pragma unroll
            for (int vt = 0; vt < 2; vt++) {
                S[dkt][vt][0] *= o.gam; S[dkt][vt][1] *= o.gam;
                S[dkt][vt][2] *= o.gam; S[dkt][vt][3] *= o.gam;
            }
#pragma unroll
        for (int ks = 0; ks < 2; ks++) {
            s8v bu[2];
#pragma unroll
            for (int vt = 0; vt < 2; vt++) {
                int v = vt * 16 + r15;
                bu[vt] = *(const s8v*)((const char*)Uplds + v * 128 + ((ks * 64 + g4 * 16) ^ ((v & 7) << 4)));
            }
#pragma unroll
            for (int dkt = 0; dkt < 2; dkt++)
#pragma unroll
                for (int vt = 0; vt < 2; vt++)
                    S[dkt][vt] = __builtin_amdgcn_mfma_f32_16x16x32_bf16(o.ak[ks * 2 + dkt], bu[vt], S[dkt][vt], 0, 0, 0);
        }
    };

    scan_load(opA, 0);
    for (int c = 0; c < NC_; c += 2) {
        scan_load(opB, (c + 1 < NC_) ? c + 1 : c);
        body(opA, c);
        if (c + 2 < NC_) scan_load(opA, c + 2);
        body(opB, c + 1);
    }
}

// ---------------- gated RMSNorm + silu(z) gate ----------------
__global__ __launch_bounds__(256) void norm_gate_k(unsigned short* __restrict__ o,
                                                   const unsigned short* __restrict__ z,
                                                   const float* __restrict__ nw) {
    int lane = threadIdx.x & 63;
    size_t bh = (size_t)blockIdx.x * 4 + (threadIdx.x >> 6);
    unsigned ov = *(unsigned*)(o + bh * 128 + lane * 2);
    float v0 = b2f((unsigned short)(ov & 0xffff)), v1 = b2f((unsigned short)(ov >> 16));
    float ss = v0 * v0 + v1 * v1;
#pragma unroll
    for (int m = 1; m < 64; m <<= 1) ss += __shfl_xor(ss, m);
    float rr = rsqrtf(ss * (1.f / 128.f) + 1e-6f);
    unsigned zv = *(const unsigned*)(z + bh * 128 + lane * 2);
    float z0 = b2f((unsigned short)(zv & 0xffff)), z1 = b2f((unsigned short)(zv >> 16));
    float o0 = v0 * rr * nw[lane * 2]     * silu(z0);
    float o1 = v1 * rr * nw[lane * 2 + 1] * silu(z1);
    *(unsigned*)(o + bh * 128 + lane * 2) = pk2(o0, o1);
}

// ---------------- launch ----------------
extern "C" void kernel_launch(void* const* d_in, const int* in_sizes, int n_in,
                              void* d_out, int out_size, void* d_ws, size_t ws_size,
                              hipStream_t stream) {
    const float* x      = (const float*)d_in[0];
    const float* W_qkv  = (const float*)d_in[1];
    const float* W_z    = (const float*)d_in[2];
    const float* W_a    = (const float*)d_in[3];
    const float* W_b    = (const float*)d_in[4];
    const float* W_out  = (const float*)d_in[5];
    const float* conv_w = (const float*)d_in[6];
    const float* dt_bias= (const float*)d_in[7];
    const float* A_log  = (const float*)d_in[8];
    const float* norm_w = (const float*)d_in[9];

    char* w = (char*)d_ws;
    const size_t MBc = (size_t)1 << 20;
    unsigned short* mixp  = (unsigned short*)(w);
    unsigned short* Wmat  = (unsigned short*)(w);
    unsigned short* knT   = (unsigned short*)(w + 32 * MBc);
    unsigned short* Aog   = (unsigned short*)(w + 48 * MBc);
    unsigned short* WqkvT = (unsigned short*)(w + 64 * MBc);
    unsigned short* obuf  = (unsigned short*)(w + 64 * MBc);
    unsigned short* kn    = (unsigned short*)(w + 80 * MBc);
    unsigned short* WzT   = (unsigned short*)(w + 96 * MBc);
    unsigned short* WoutT = (unsigned short*)(w + 96 * MBc);
    unsigned short* xb    = (unsigned short*)(w + 112 * MBc);
    unsigned short* qn    = (unsigned short*)(w + 112 * MBc);
    unsigned short* vv    = (unsigned short*)(w + 128 * MBc);
    unsigned short* zb    = (unsigned short*)(w + 160 * MBc);
    float* gbuf  = (float*)(w + 192 * MBc);
    float* bbuf  = (float*)(w + 192 * MBc + 512 * 1024);
    float* expG  = (float*)(w + 192 * MBc + 1024 * 1024);
    float* expGr = (float*)(w + 192 * MBc + 1536 * 1024);
    float* WabP  = (float*)(w + 194 * MBc);

    pack_ab_k<<<512, 256, 0, stream>>>(W_a, W_b, WabP);
    cast_bf16_k<<<(BT_ * DIM_ / 8 + 255) / 256, 256, 0, stream>>>(x, xb, BT_ * DIM_ / 8);
    ab_gbeta_k<<<BT_ / 4, 256, 0, stream>>>(x, WabP, dt_bias, A_log, gbuf, bbuf);
    transpose_cast_k<<<dim3(CONV_DIM_ / 32, DIM_ / 32), 256, 0, stream>>>(W_qkv, WqkvT, DIM_, CONV_DIM_);
    transpose_cast_k<<<dim3(VAL_DIM_ / 32, DIM_ / 32), 256, 0, stream>>>(W_z, WzT, DIM_, VAL_DIM_);
    gemm256_bt_k<1><<<dim3(CONV_DIM_ / 256, BT_ / 256), 512, 131072, stream>>>(xb, WqkvT, mixp, BT_, CONV_DIM_, DIM_);
    gemm256_bt_k<1><<<dim3(VAL_DIM_ / 256, BT_ / 256), 512, 131072, stream>>>(xb, WzT, zb, BT_, VAL_DIM_, DIM_);
    transpose_cast_k<<<dim3(DIM_ / 32, VAL_DIM_ / 32), 256, 0, stream>>>(W_out, WoutT, VAL_DIM_, DIM_);
    conv_fused_k<<<dim3(BT_, CONV_DIM_ / 512), 256, 0, stream>>>(mixp, conv_w, qn, kn, vv);
    chunk_pre_k<<<dim3(NC_, HV_ / 2, B_), 256, 0, stream>>>(qn, kn, vv, gbuf, bbuf,
                                                            Wmat, Aog, knT, expG, expGr);
    chunk_scan_k<<<B_ * HV_ * 4, 256, 0, stream>>>(qn, knT, vv, Wmat, Aog, expG, expGr, obuf);
    norm_gate_k<<<BT_ * HV_ / 4, 256, 0, stream>>>(obuf, zb, norm_w);
    gemm256_bt_k<0><<<dim3(DIM_ / 256, BT_ / 256), 512, 131072, stream>>>(obuf, WoutT, d_out, BT_, DIM_, VAL_DIM_);
}

// Round 16
// 646.908 us; speedup vs baseline: 1.0586x; 1.0586x over previous
//
#include <hip/hip_runtime.h>
#include <hip/hip_bf16.h>
#include <cstdint>
#include <cstddef>

#define DIM_ 2048
#define HV_ 32
#define HK_ 16
#define DK_ 128
#define DV_ 128
#define KW_ 4
#define KEY_DIM_ 2048
#define VAL_DIM_ 4096
#define CONV_DIM_ 8192
#define B_ 2
#define T_ 2048
#define BT_ 4096
#define CH_ 64
#define NC_ (T_ / CH_)

typedef short s8v __attribute__((ext_vector_type(8)));
typedef float f4v __attribute__((ext_vector_type(4)));

__device__ __forceinline__ unsigned short f2b(float f) {
    union { float f; unsigned u; } c; c.f = f;
    unsigned u = c.u;
    return (unsigned short)((u + 0x7fffu + ((u >> 16) & 1u)) >> 16);
}
__device__ __forceinline__ float b2f(unsigned short s) {
    union { unsigned u; float f; } c; c.u = ((unsigned)s) << 16;
    return c.f;
}
__device__ __forceinline__ unsigned int pk2(float a, float b) {
    return (unsigned)f2b(a) | ((unsigned)f2b(b) << 16);
}
__device__ __forceinline__ float silu(float x) { return x / (1.f + expf(-x)); }

// ---------------- cast f32 -> bf16 ----------------
__global__ void cast_bf16_k(const float* __restrict__ in, unsigned short* __restrict__ out, int n8) {
    int i = blockIdx.x * blockDim.x + threadIdx.x;
    if (i >= n8) return;
    int base = i * 8;
    f4v a = *(const f4v*)(in + base);
    f4v b = *(const f4v*)(in + base + 4);
    s8v o;
    o[0] = (short)f2b(a[0]); o[1] = (short)f2b(a[1]); o[2] = (short)f2b(a[2]); o[3] = (short)f2b(a[3]);
    o[4] = (short)f2b(b[0]); o[5] = (short)f2b(b[1]); o[6] = (short)f2b(b[2]); o[7] = (short)f2b(b[3]);
    *(s8v*)(out + base) = o;
}

// ---------------- transpose + cast ----------------
__global__ void transpose_cast_k(const float* __restrict__ in, unsigned short* __restrict__ out,
                                 int R, int C) {
    __shared__ float tile[32][33];
    int c0 = blockIdx.x * 32, r0 = blockIdx.y * 32;
    int tx = threadIdx.x & 31, ty = threadIdx.x >> 5;
#pragma unroll
    for (int j = 0; j < 32; j += 8)
        tile[ty + j][tx] = in[(size_t)(r0 + ty + j) * C + c0 + tx];
    __syncthreads();
#pragma unroll
    for (int j = 0; j < 32; j += 8)
        out[(size_t)(c0 + ty + j) * R + r0 + tx] = f2b(tile[tx][ty + j]);
}

// ---------------- pack W_a||W_b -> WabP[512][64][4] f32 ----------------
__global__ void pack_ab_k(const float* __restrict__ Wa, const float* __restrict__ Wb,
                          float* __restrict__ WabP) {
    int idx = blockIdx.x * 256 + threadIdx.x;
    int k = idx >> 6;
    int c = idx & 63;
    float v = (c < 32) ? Wa[(size_t)k * 32 + c] : Wb[(size_t)k * 32 + (c - 32)];
    WabP[((size_t)(k >> 2) * 64 + c) * 4 + (k & 3)] = v;
}

// ================ 256x256 8-phase bf16 GEMM (m201 template, plain HIP) ================
template <int OUT_BF16>
__global__ __launch_bounds__(512) void gemm256_bt_k(const unsigned short* __restrict__ A,
                                                    const unsigned short* __restrict__ BT,
                                                    void* __restrict__ Cv,
                                                    int M, int N, int K) {
    extern __shared__ char lds[];   // 131072 B
    const int tid = threadIdx.x;
    const int wid = tid >> 6, lane = tid & 63;
    const int wm = wid >> 2, wn = wid & 3;
    const int r15 = lane & 15, g4 = lane >> 4;
    const int m0 = blockIdx.y * 256, n0 = blockIdx.x * 256;
    const int NT = K >> 6;

    f4v acc[8][4];
#pragma unroll
    for (int i = 0; i < 8; i++)
#pragma unroll
        for (int j = 0; j < 4; j++) acc[i][j] = (f4v){0.f, 0.f, 0.f, 0.f};

    const int i8 = lane >> 3;
    const int colb = (lane & 7) << 4;

    auto stage = [&](int unit, int t) {
        int buf = t & 1;
        int matB = (unit == 1 || unit == 2);
        int rs0;
        if (unit == 0)      rs0 = wid * 8;
        else if (unit == 3) rs0 = 64 + wid * 8;
        else                rs0 = (wid < 4 ? wid * 8 : 64 + (wid - 4) * 8) + (unit == 2 ? 32 : 0);
#pragma unroll
        for (int p = 0; p < 2; p++) {
            int rowst = rs0 + p * 128;
            int row = rowst + i8;
            int scol = colb ^ ((row & 7) << 4);
            const unsigned short* g = (matB ? BT + (size_t)(n0 + row) * K
                                            : A  + (size_t)(m0 + row) * K)
                                      + t * 64 + (scol >> 1);
            char* l = lds + buf * 65536 + matB * 32768 + rowst * 128;
            __builtin_amdgcn_global_load_lds(
                (const __attribute__((address_space(1))) unsigned int*)g,
                (__attribute__((address_space(3))) unsigned int*)l, 16, 0, 0);
        }
    };
    auto loadA = [&](s8v* af, int mh, int buf) {
        char* base = lds + buf * 65536;
#pragma unroll
        for (int mi = 0; mi < 4; mi++) {
            int row = wm * 128 + mh * 64 + mi * 16 + r15;
#pragma unroll
            for (int kk = 0; kk < 2; kk++) {
                int off = row * 128 + ((kk * 64 + g4 * 16) ^ ((row & 7) << 4));
                af[mi * 2 + kk] = *(const s8v*)(base + off);
            }
        }
    };
    auto loadB = [&](s8v* bf, int nh, int buf) {
        char* base = lds + buf * 65536 + 32768;
#pragma unroll
        for (int ni = 0; ni < 2; ni++) {
            int row = wn * 64 + nh * 32 + ni * 16 + r15;
#pragma unroll
            for (int kk = 0; kk < 2; kk++) {
                int off = row * 128 + ((kk * 64 + g4 * 16) ^ ((row & 7) << 4));
                bf[ni * 2 + kk] = *(const s8v*)(base + off);
            }
        }
    };
    auto mfma16 = [&](s8v* af, s8v* bf, int mh, int nh) {
#pragma unroll
        for (int mi = 0; mi < 4; mi++)
#pragma unroll
            for (int ni = 0; ni < 2; ni++)
#pragma unroll
                for (int kk = 0; kk < 2; kk++)
                    acc[mh * 4 + mi][nh * 2 + ni] = __builtin_amdgcn_mfma_f32_16x16x32_bf16(
                        af[mi * 2 + kk], bf[ni * 2 + kk], acc[mh * 4 + mi][nh * 2 + ni], 0, 0, 0);
    };

    stage(0, 0); stage(1, 0); stage(2, 0); stage(3, 0);
    stage(0, 1); stage(1, 1); stage(2, 1);
    asm volatile("s_waitcnt vmcnt(6)" ::: "memory");
    __builtin_amdgcn_s_barrier();

    for (int u = 0; u < NT; u++) {
        int buf = u & 1;
        s8v afE[8], afO[8], bfE[4], bfO[4];

        loadA(afE, 0, buf); loadB(bfE, 0, buf);
        if (u + 1 < NT) stage(3, u + 1);
        __builtin_amdgcn_s_barrier();
        asm volatile("s_waitcnt lgkmcnt(0)" ::: "memory");
        __builtin_amdgcn_sched_barrier(0);
        __builtin_amdgcn_s_setprio(1);
        mfma16(afE, bfE, 0, 0);
        __builtin_amdgcn_s_setprio(0);
        __builtin_amdgcn_s_barrier();

        loadB(bfO, 1, buf);
        if (u + 2 < NT) stage(0, u + 2);
        __builtin_amdgcn_s_barrier();
        asm volatile("s_waitcnt lgkmcnt(0)" ::: "memory");
        __builtin_amdgcn_sched_barrier(0);
        __builtin_amdgcn_s_setprio(1);
        mfma16(afE, bfO, 0, 1);
        __builtin_amdgcn_s_setprio(0);
        __builtin_amdgcn_s_barrier();

        loadA(afO, 1, buf);
        if (u + 2 < NT) stage(1, u + 2);
        __builtin_amdgcn_s_barrier();
        asm volatile("s_waitcnt lgkmcnt(0)" ::: "memory");
        __builtin_amdgcn_sched_barrier(0);
        __builtin_amdgcn_s_setprio(1);
        mfma16(afO, bfO, 1, 1);
        __builtin_amdgcn_s_setprio(0);
        __builtin_amdgcn_s_barrier();

        if (u + 2 < NT) stage(2, u + 2);
        __builtin_amdgcn_s_barrier();
        __builtin_amdgcn_s_setprio(1);
        mfma16(afO, bfE, 1, 0);
        __builtin_amdgcn_s_setprio(0);
        if (u == NT - 2) asm volatile("s_waitcnt vmcnt(0)" ::: "memory");
        else             asm volatile("s_waitcnt vmcnt(6)" ::: "memory");
        __builtin_amdgcn_s_barrier();
    }

#pragma unroll
    for (int mi = 0; mi < 8; mi++)
#pragma unroll
        for (int ni = 0; ni < 4; ni++) {
            int row = m0 + wm * 128 + mi * 16 + g4 * 4;
            int col = n0 + wn * 64 + ni * 16 + r15;
#pragma unroll
            for (int r = 0; r < 4; r++) {
                float v = acc[mi][ni][r];
                if (OUT_BF16)
                    ((unsigned short*)Cv)[(size_t)(row + r) * N + col] = f2b(v);
                else
                    ((float*)Cv)[(size_t)(row + r) * N + col] = v;
            }
        }
}

// ---------------- a,b GEMM (exact f32) + g/beta ----------------
__global__ __launch_bounds__(256) void ab_gbeta_k(const float* __restrict__ x,
                                                  const float* __restrict__ WabP,
                                                  const float* __restrict__ dt_bias,
                                                  const float* __restrict__ A_log,
                                                  float* __restrict__ g, float* __restrict__ beta) {
    const int c = threadIdx.x & 63;
    const int rg = __builtin_amdgcn_readfirstlane(threadIdx.x >> 6);
    const int row = blockIdx.x * 4 + rg;
    const float* xp = x + (size_t)row * 2048;
    const float* wp = WabP + c * 4;
    float acc0 = 0.f, acc1 = 0.f;
#pragma unroll 4
    for (int kb = 0; kb < 512; kb += 2) {
        f4v w0 = *(const f4v*)(wp + (size_t)kb * 256);
        f4v w1 = *(const f4v*)(wp + (size_t)(kb + 1) * 256);
        f4v x0 = *(const f4v*)(xp + kb * 4);
        f4v x1 = *(const f4v*)(xp + kb * 4 + 4);
        acc0 += x0[0] * w0[0] + x0[1] * w0[1] + x0[2] * w0[2] + x0[3] * w0[3];
        acc1 += x1[0] * w1[0] + x1[1] * w1[1] + x1[2] * w1[2] + x1[3] * w1[3];
    }
    float tot = acc0 + acc1;
    if (c < 32) {
        float av = tot + dt_bias[c];
        float sp = (av > 20.f) ? av : log1pf(expf(av));
        g[(size_t)row * 32 + c] = -expf(A_log[c]) * sp;
    } else {
        beta[(size_t)row * 32 + (c - 32)] = 1.f / (1.f + expf(-tot));
    }
}

// ---------------- conv + silu + l2norm + split: 4 timesteps/thread (R13 version) ----------------
// Attribution (R12-R15 A/Bs): conv4t = -19us (4x fewer mixp reads beats TLP loss).
__global__ __launch_bounds__(256) void conv_fused_k(const unsigned short* __restrict__ mixp,
                                                    const float* __restrict__ convw,
                                                    unsigned short* __restrict__ qn,
                                                    unsigned short* __restrict__ kn,
                                                    unsigned short* __restrict__ vv) {
    int btid0 = blockIdx.x * 4;
    int seqt0 = btid0 & (T_ - 1);
    int c = (blockIdx.y << 9) + (threadIdx.x << 1);
    const unsigned short* base = mixp + (size_t)btid0 * CONV_DIM_ + c;
    unsigned u[7];
#pragma unroll
    for (int j = 0; j < 7; j++)
        u[j] = (seqt0 + j >= 3) ? *(const unsigned*)(base + (ptrdiff_t)(j - 3) * CONV_DIM_) : 0u;
    f4v w0 = *(const f4v*)(convw + (size_t)c * 4);
    f4v w1 = *(const f4v*)(convw + (size_t)c * 4 + 4);
    float v0[4], v1[4];
#pragma unroll
    for (int tt = 0; tt < 4; tt++) {
        float a0 = 0.f, a1 = 0.f;
#pragma unroll
        for (int tau = 0; tau < 4; tau++) {
            unsigned m = u[tt + tau];
            a0 += b2f((unsigned short)(m & 0xffff)) * w0[tau];
            a1 += b2f((unsigned short)(m >> 16)) * w1[tau];
        }
        v0[tt] = silu(a0); v1[tt] = silu(a1);
    }
    if (c < 2 * KEY_DIM_) {
        int head = (c >> 7) & 15, d = c & 127;
        bool isq = c < KEY_DIM_;
        unsigned short* dst = isq ? qn : kn;
#pragma unroll
        for (int tt = 0; tt < 4; tt++) {
            float ss = v0[tt] * v0[tt] + v1[tt] * v1[tt];
#pragma unroll
            for (int m = 1; m < 64; m <<= 1) ss += __shfl_xor(ss, m);
            float scale = rsqrtf(ss + 1e-6f);
            if (isq) scale *= 0.08838834764831845f;
            *(unsigned*)(dst + ((size_t)(btid0 + tt) * HK_ + head) * DK_ + d) = pk2(v0[tt] * scale, v1[tt] * scale);
        }
    } else {
#pragma unroll
        for (int tt = 0; tt < 4; tt++)
            *(unsigned*)(vv + (size_t)(btid0 + tt) * VAL_DIM_ + (c - 2 * KEY_DIM_)) = pk2(v0[tt], v1[tt]);
    }
}

// ================= chunked delta rule: parallel precompute (h-pair merged; R12 trisolve) =================
// Attribution (R12-R15 A/Bs): per-I trisolve = +31us despite fewer barriers -> reverted
// to R12's per-(I,J) form (AT[64][68], STmp[16][17]).
__global__ __launch_bounds__(256) void chunk_pre_k(
    const unsigned short* __restrict__ qn, const unsigned short* __restrict__ kn,
    unsigned short* __restrict__ vv,
    const float* __restrict__ g, const float* __restrict__ beta,
    unsigned short* __restrict__ Wg, unsigned short* __restrict__ Aog,
    unsigned short* __restrict__ knT, float* __restrict__ expG, float* __restrict__ expGr)
{
    const int c = blockIdx.x, hp = blockIdx.y, b = blockIdx.z;
    const int tid = threadIdx.x, wid = tid >> 6, lane = tid & 63;
    const int r15 = lane & 15, g4 = lane >> 4;

    __shared__ __attribute__((aligned(16))) unsigned short Klds[64 * 128];
    __shared__ __attribute__((aligned(16))) unsigned short Xlds[128 * 64];
    __shared__ float AT[64][68];
    __shared__ float STmp[16][17];
    __shared__ float Gl2[2][64], Bl2[2][64], EG2[2][64];

    const size_t t0 = (size_t)b * T_ + (size_t)c * 64;

#pragma unroll
    for (int p = 0; p < 4; p++) {
        int row = p * 16 + (tid >> 4);
        int colB = (tid & 15) << 4;
        int sw = colB ^ ((row & 7) << 4);
        s8v kv = *(const s8v*)(kn + ((t0 + row) * HK_ + hp) * DK_ + (colB >> 1));
        *(s8v*)((char*)Klds + row * 256 + sw) = kv;
        s8v qv = *(const s8v*)(qn + ((t0 + row) * HK_ + hp) * DK_ + (colB >> 1));
        *(s8v*)((char*)Xlds + row * 256 + sw) = qv;
    }
    if (wid < 2) {
        int h = hp * 2 + wid;
        float v = g[(t0 + lane) * HV_ + h];
        float bv = beta[(t0 + lane) * HV_ + h];
#pragma unroll
        for (int off = 1; off < 64; off <<= 1) {
            float n = __shfl_up(v, off);
            if (lane >= off) v += n;
        }
        float Gn = __shfl(v, 63);
        float e1 = expf(v), e2 = expf(Gn - v);
        Gl2[wid][lane] = v;
        Bl2[wid][lane] = bv;
        EG2[wid][lane] = e1;
        size_t cbk = ((size_t)(b * 32 + h) * 32 + c);
        expG[cbk * 64 + lane] = e1;
        expGr[cbk * 64 + lane] = e2;
    }
    __syncthreads();

    f4v kkv[4], qkv[4];
#pragma unroll
    for (int jt = 0; jt < 4; jt++) { kkv[jt] = (f4v){0,0,0,0}; qkv[jt] = (f4v){0,0,0,0}; }
    const int arow = wid * 16 + r15;
#pragma unroll
    for (int ks = 0; ks < 4; ks++) {
        int abyte = arow * 256 + ((ks * 64 + (g4 << 4)) ^ ((arow & 7) << 4));
        s8v ak = *(const s8v*)((const char*)Klds + abyte);
        s8v aq = *(const s8v*)((const char*)Xlds + abyte);
#pragma unroll
        for (int jt = 0; jt < 4; jt++) {
            int jrow = jt * 16 + r15;
            int bbyte = jrow * 256 + ((ks * 64 + (g4 << 4)) ^ ((jrow & 7) << 4));
            s8v bk = *(const s8v*)((const char*)Klds + bbyte);
            kkv[jt] = __builtin_amdgcn_mfma_f32_16x16x32_bf16(ak, bk, kkv[jt], 0, 0, 0);
            qkv[jt] = __builtin_amdgcn_mfma_f32_16x16x32_bf16(aq, bk, qkv[jt], 0, 0, 0);
        }
    }

    for (int hh = 0; hh < 2; hh++) {
        const int h = hp * 2 + hh;
        const size_t cbk = ((size_t)(b * 32 + h) * 32 + c);

#pragma unroll
        for (int jt = 0; jt < 4; jt++) {
#pragma unroll
            for (int r = 0; r < 4; r++) {
                int i = wid * 16 + g4 * 4 + r;
                int j = jt * 16 + r15;
                float em = expf(fminf(Gl2[hh][i] - Gl2[hh][j], 0.f));
                AT[i][j] = (j < i) ? Bl2[hh][i] * em * kkv[jt][r] : 0.f;
                float ao = (j <= i) ? em * qkv[jt][r] : 0.f;
                Aog[cbk * 4096 + i * 64 + j] = f2b(ao);
            }
        }
        __syncthreads();

        for (int u = tid; u < 1024; u += 256) {
            int row = u >> 4, v0i = (u & 15) << 3;
            s8v vx = *(const s8v*)(vv + (t0 + row) * VAL_DIM_ + h * 128 + v0i);
            float bt = Bl2[hh][row];
#pragma unroll
            for (int e = 0; e < 8; e++) {
                int v = v0i + e;
                *(unsigned short*)((char*)Xlds + v * 128 + ((row * 2) ^ ((v & 7) << 4))) =
                    f2b(b2f((unsigned short)vx[e]) * bt);
            }
        }
        if (hh == 0) {
            int dk = tid & 127, th = (tid >> 7) << 5;
            size_t basek = ((size_t)(b * 16 + hp) * 128 + dk) * (size_t)T_ + (size_t)c * 64 + th;
#pragma unroll
            for (int t8 = 0; t8 < 4; t8++) {
                s8v kv;
#pragma unroll
                for (int e = 0; e < 8; e++) {
                    int tt = th + t8 * 8 + e;
                    kv[e] = (short)*(const unsigned short*)((const char*)Klds + tt * 256 + ((dk * 2) ^ ((tt & 7) << 4)));
                }
                *(s8v*)(knT + basek + t8 * 8) = kv;
            }
        }
        __syncthreads();

        if (lane < 16) {
            int r0 = wid * 16, col = lane;
#pragma unroll
            for (int i = 0; i < 16; i++) {
                float s = 0.f;
                for (int j = 0; j < i; j++) s += AT[r0 + i][r0 + j] * AT[r0 + j][r0 + col];
                AT[r0 + i][r0 + col] = ((col == i) ? 1.f : 0.f) - s;
            }
        }
        __syncthreads();

        // c3 (R12): per-(I,J) off-diagonal blocks, ascending J
        {
            int ii = tid >> 4, jj = tid & 15;
            for (int I = 1; I < 4; I++)
                for (int J = 0; J < I; J++) {
                    float s = 0.f;
                    for (int K = J; K < I; K++) {
#pragma unroll
                        for (int m = 0; m < 16; m++)
                            s += AT[16 * I + ii][16 * K + m] * AT[16 * K + m][16 * J + jj];
                    }
                    STmp[ii][jj] = s;
                    __syncthreads();
                    float y = 0.f;
#pragma unroll
                    for (int m = 0; m < 16; m++) y += AT[16 * I + ii][16 * I + m] * STmp[m][jj];
                    __syncthreads();
                    AT[16 * I + ii][16 * J + jj] = -y;
                    __syncthreads();
                }
        }

        f4v tb[8];
#pragma unroll
        for (int vt = 0; vt < 8; vt++) tb[vt] = (f4v){0,0,0,0};
#pragma unroll
        for (int ks = 0; ks < 2; ks++) {
            s8v ta;
#pragma unroll
            for (int e = 0; e < 8; e++) ta[e] = (short)f2b(AT[arow][ks * 32 + g4 * 8 + e]);
#pragma unroll
            for (int vt = 0; vt < 8; vt++) {
                int v = vt * 16 + r15;
                int bbyte = v * 128 + ((ks * 64 + (g4 << 4)) ^ ((v & 7) << 4));
                s8v bv = *(const s8v*)((const char*)Xlds + bbyte);
                tb[vt] = __builtin_amdgcn_mfma_f32_16x16x32_bf16(ta, bv, tb[vt], 0, 0, 0);
            }
        }
#pragma unroll
        for (int vt = 0; vt < 8; vt++)
#pragma unroll
            for (int r = 0; r < 4; r++) {
                int i = wid * 16 + g4 * 4 + r, v = vt * 16 + r15;
                vv[(t0 + i) * VAL_DIM_ + h * 128 + v] = f2b(tb[vt][r]);
            }
        __syncthreads();

        {
            int dk = tid & 127;
            int tb0 = (tid >> 7) << 5;
#pragma unroll
            for (int t8 = 0; t8 < 4; t8++) {
                int tbase = tb0 + t8 * 8;
                s8v kw;
#pragma unroll
                for (int e = 0; e < 8; e++) {
                    int t = tbase + e;
                    float kv = b2f(*(const unsigned short*)((const char*)Klds + t * 256 + ((dk * 2) ^ ((t & 7) << 4))));
                    kw[e] = (short)f2b(kv * Bl2[hh][t] * EG2[hh][t]);
                }
                *(s8v*)((char*)Xlds + dk * 128 + ((tbase * 2) ^ ((dk & 7) << 4))) = kw;
            }
        }
        __syncthreads();

        f4v wm[8];
#pragma unroll
        for (int dt = 0; dt < 8; dt++) wm[dt] = (f4v){0,0,0,0};
#pragma unroll
        for (int ks = 0; ks < 2; ks++) {
            s8v ta;
#pragma unroll
            for (int e = 0; e < 8; e++) ta[e] = (short)f2b(AT[arow][ks * 32 + g4 * 8 + e]);
#pragma unroll
            for (int dt = 0; dt < 8; dt++) {
                int dkr = dt * 16 + r15;
                int bbyte = dkr * 128 + ((ks * 64 + (g4 << 4)) ^ ((dkr & 7) << 4));
                s8v bw = *(const s8v*)((const char*)Xlds + bbyte);
                wm[dt] = __builtin_amdgcn_mfma_f32_16x16x32_bf16(ta, bw, wm[dt], 0, 0, 0);
            }
        }
#pragma unroll
        for (int dt = 0; dt < 8; dt++)
#pragma unroll
            for (int r = 0; r < 4; r++) {
                int i = wid * 16 + g4 * 4 + r, dk = dt * 16 + r15;
                Wg[cbk * 8192 + i * 128 + dk] = f2b(wm[dt][r]);
            }
        __syncthreads();
    }
}

// ================= chunked delta rule: sequential scan =================
__global__ __launch_bounds__(256) void chunk_scan_k(
    const unsigned short* __restrict__ qn, const unsigned short* __restrict__ knT,
    const unsigned short* __restrict__ tbv,
    const unsigned short* __restrict__ Wg, const unsigned short* __restrict__ Aog,
    const float* __restrict__ expG, const float* __restrict__ expGr,
    unsigned short* __restrict__ ob)
{
    const int bx = blockIdx.x;
    const int vq = bx & 3, h = (bx >> 2) & 31, b = bx >> 7;
    const int hk = h >> 1;
    const int tid = threadIdx.x, wid = tid >> 6, lane = tid & 63;
    const int r15 = lane & 15, g4 = lane >> 4;

    __shared__ __attribute__((aligned(16))) unsigned short Slds[32 * 128];
    __shared__ __attribute__((aligned(16))) unsigned short Ulds[32 * 64];
    __shared__ __attribute__((aligned(16))) unsigned short Uplds[32 * 64];

    f4v S[2][2];
#pragma unroll
    for (int i = 0; i < 2; i++)
#pragma unroll
        for (int j = 0; j < 2; j++) S[i][j] = (f4v){0,0,0,0};

    struct ScanOps {
        s8v aw[4], aa[2], ak[4], q0[4];
        float tv[8], egr4[4], egi, gam;
    };
    ScanOps opA, opB;

    const unsigned short* kpbase = knT + ((size_t)(b * 16 + hk) * 128) * (size_t)T_;

    auto scan_load = [&](ScanOps& o, int c) {
        const size_t cbk = ((size_t)(b * 32 + h) * 32 + c);
        const size_t t0 = (size_t)b * T_ + (size_t)c * 64;
        const unsigned short* wp = Wg + cbk * 8192 + (size_t)(wid * 16 + r15) * 128;
#pragma unroll
        for (int ks = 0; ks < 4; ks++) o.aw[ks] = *(const s8v*)(wp + ks * 32 + g4 * 8);
        const unsigned short* ap = Aog + cbk * 4096 + (size_t)(wid * 16 + r15) * 64;
#pragma unroll
        for (int ks = 0; ks < 2; ks++) o.aa[ks] = *(const s8v*)(ap + ks * 32 + g4 * 8);
#pragma unroll
        for (int ks = 0; ks < 2; ks++)
#pragma unroll
            for (int dkt = 0; dkt < 2; dkt++)
                o.ak[ks * 2 + dkt] = *(const s8v*)(kpbase +
                    (size_t)((wid * 2 + dkt) * 16 + r15) * T_ + (size_t)c * 64 + ks * 32 + g4 * 8);
        const unsigned short* qp = qn + ((t0 + wid * 16 + r15) * HK_ + hk) * DK_;
#pragma unroll
        for (int ks = 0; ks < 4; ks++) o.q0[ks] = *(const s8v*)(qp + ks * 32 + g4 * 8);
#pragma unroll
        for (int vt = 0; vt < 2; vt++)
#pragma unroll
            for (int r = 0; r < 4; r++) {
                int t = wid * 16 + g4 * 4 + r;
                o.tv[vt * 4 + r] = b2f(tbv[(t0 + t) * VAL_DIM_ + h * 128 + vq * 32 + vt * 16 + r15]);
            }
#pragma unroll
        for (int r = 0; r < 4; r++) o.egr4[r] = expGr[cbk * 64 + wid * 16 + g4 * 4 + r];
        o.egi = expG[cbk * 64 + wid * 16 + r15];
        o.gam = expG[cbk * 64 + 63];
    };

    auto body = [&](ScanOps& o, int c) {
#pragma unroll
        for (int dkt = 0; dkt < 2; dkt++)
#pragma unroll
            for (int vt = 0; vt < 2; vt++) {
                int v = vt * 16 + r15;
                int dkb = ((wid * 2 + dkt) * 16 + g4 * 4) * 2;
                int sw = (v & 7) << 4;
                *(unsigned int*)((char*)Slds + v * 256 + ((dkb) ^ sw))     = pk2(S[dkt][vt][0], S[dkt][vt][1]);
                *(unsigned int*)((char*)Slds + v * 256 + ((dkb + 4) ^ sw)) = pk2(S[dkt][vt][2], S[dkt][vt][3]);
            }
        __syncthreads();

        f4v P[2]; P[0] = (f4v){0,0,0,0}; P[1] = (f4v){0,0,0,0};
        s8v sf[4][2];
#pragma unroll
        for (int ks = 0; ks < 4; ks++)
#pragma unroll
            for (int vt = 0; vt < 2; vt++) {
                int v = vt * 16 + r15;
                sf[ks][vt] = *(const s8v*)((const char*)Slds + v * 256 + ((ks * 64 + g4 * 16) ^ ((v & 7) << 4)));
                P[vt] = __builtin_amdgcn_mfma_f32_16x16x32_bf16(o.aw[ks], sf[ks][vt], P[vt], 0, 0, 0);
            }
#pragma unroll
        for (int vt = 0; vt < 2; vt++) {
            float uu[4], up[4];
#pragma unroll
            for (int r = 0; r < 4; r++) {
                uu[r] = o.tv[vt * 4 + r] - P[vt][r];
                up[r] = uu[r] * o.egr4[r];
            }
            int v = vt * 16 + r15;
            int tb2 = (wid * 16 + g4 * 4) * 2;
            int sw = (v & 7) << 4;
            *(unsigned int*)((char*)Ulds  + v * 128 + ((tb2) ^ sw))     = pk2(uu[0], uu[1]);
            *(unsigned int*)((char*)Ulds  + v * 128 + ((tb2 + 4) ^ sw)) = pk2(uu[2], uu[3]);
            *(unsigned int*)((char*)Uplds + v * 128 + ((tb2) ^ sw))     = pk2(up[0], up[1]);
            *(unsigned int*)((char*)Uplds + v * 128 + ((tb2 + 4) ^ sw)) = pk2(up[2], up[3]);
        }

        f4v O[2]; O[0] = (f4v){0,0,0,0}; O[1] = (f4v){0,0,0,0};
#pragma unroll
        for (int ks = 0; ks < 4; ks++) {
            s8v qg;
#pragma unroll
            for (int e = 0; e < 8; e++) qg[e] = (short)f2b(b2f((unsigned short)o.q0[ks][e]) * o.egi);
#pragma unroll
            for (int vt = 0; vt < 2; vt++)
                O[vt] = __builtin_amdgcn_mfma_f32_16x16x32_bf16(qg, sf[ks][vt], O[vt], 0, 0, 0);
        }
        __syncthreads();

#pragma unroll
        for (int ks = 0; ks < 2; ks++)
#pragma unroll
            for (int vt = 0; vt < 2; vt++) {
                int v = vt * 16 + r15;
                s8v bu = *(const s8v*)((const char*)Ulds + v * 128 + ((ks * 64 + g4 * 16) ^ ((v & 7) << 4)));
                O[vt] = __builtin_amdgcn_mfma_f32_16x16x32_bf16(o.aa[ks], bu, O[vt], 0, 0, 0);
            }
#pragma unroll
        for (int vt = 0; vt < 2; vt++)
#pragma unroll
            for (int r = 0; r < 4; r++) {
                int t = c * 64 + wid * 16 + g4 * 4 + r;
                ob[((size_t)b * T_ + t) * VAL_DIM_ + h * 128 + vq * 32 + vt * 16 + r15] = f2b(O[vt][r]);
            }

#pragma unroll
        for (int dkt = 0; dkt < 2; dkt++)
#pragma unroll
            for (int vt = 0; vt < 2; vt++) {
                S[dkt][vt][0] *= o.gam; S[dkt][vt][1] *= o.gam;
                S[dkt][vt][2] *= o.gam; S[dkt][vt][3] *= o.gam;
            }
#pragma unroll
        for (int ks = 0; ks < 2; ks++) {
            s8v bu[2];
#pragma unroll
            for (int vt = 0; vt < 2; vt++) {
                int v = vt * 16 + r15;
                bu[vt] = *(const s8v*)((const char*)Uplds + v * 128 + ((ks * 64 + g4 * 16) ^ ((v & 7) << 4)));
            }
#pragma unroll
            for (int dkt = 0; dkt < 2; dkt++)
#pragma unroll
                for (int vt = 0; vt < 2; vt++)
                    S[dkt][vt] = __builtin_amdgcn_mfma_f32_16x16x32_bf16(o.ak[ks * 2 + dkt], bu[vt], S[dkt][vt], 0, 0, 0);
        }
    };

    scan_load(opA, 0);
    for (int c = 0; c < NC_; c += 2) {
        scan_load(opB, (c + 1 < NC_) ? c + 1 : c);
        body(opA, c);
        if (c + 2 < NC_) scan_load(opA, c + 2);
        body(opB, c + 1);
    }
}

// ---------------- gated RMSNorm + silu(z) gate ----------------
__global__ __launch_bounds__(256) void norm_gate_k(unsigned short* __restrict__ o,
                                                   const unsigned short* __restrict__ z,
                                                   const float* __restrict__ nw) {
    int lane = threadIdx.x & 63;
    size_t bh = (size_t)blockIdx.x * 4 + (threadIdx.x >> 6);
    unsigned ov = *(unsigned*)(o + bh * 128 + lane * 2);
    float v0 = b2f((unsigned short)(ov & 0xffff)), v1 = b2f((unsigned short)(ov >> 16));
    float ss = v0 * v0 + v1 * v1;
#pragma unroll
    for (int m = 1; m < 64; m <<= 1) ss += __shfl_xor(ss, m);
    float rr = rsqrtf(ss * (1.f / 128.f) + 1e-6f);
    unsigned zv = *(const unsigned*)(z + bh * 128 + lane * 2);
    float z0 = b2f((unsigned short)(zv & 0xffff)), z1 = b2f((unsigned short)(zv >> 16));
    float o0 = v0 * rr * nw[lane * 2]     * silu(z0);
    float o1 = v1 * rr * nw[lane * 2 + 1] * silu(z1);
    *(unsigned*)(o + bh * 128 + lane * 2) = pk2(o0, o1);
}

// ---------------- launch ----------------
extern "C" void kernel_launch(void* const* d_in, const int* in_sizes, int n_in,
                              void* d_out, int out_size, void* d_ws, size_t ws_size,
                              hipStream_t stream) {
    const float* x      = (const float*)d_in[0];
    const float* W_qkv  = (const float*)d_in[1];
    const float* W_z    = (const float*)d_in[2];
    const float* W_a    = (const float*)d_in[3];
    const float* W_b    = (const float*)d_in[4];
    const float* W_out  = (const float*)d_in[5];
    const float* conv_w = (const float*)d_in[6];
    const float* dt_bias= (const float*)d_in[7];
    const float* A_log  = (const float*)d_in[8];
    const float* norm_w = (const float*)d_in[9];

    char* w = (char*)d_ws;
    const size_t MBc = (size_t)1 << 20;
    unsigned short* mixp  = (unsigned short*)(w);
    unsigned short* Wmat  = (unsigned short*)(w);
    unsigned short* knT   = (unsigned short*)(w + 32 * MBc);
    unsigned short* Aog   = (unsigned short*)(w + 48 * MBc);
    unsigned short* WqkvT = (unsigned short*)(w + 64 * MBc);
    unsigned short* obuf  = (unsigned short*)(w + 64 * MBc);
    unsigned short* kn    = (unsigned short*)(w + 80 * MBc);
    unsigned short* WzT   = (unsigned short*)(w + 96 * MBc);
    unsigned short* WoutT = (unsigned short*)(w + 96 * MBc);
    unsigned short* xb    = (unsigned short*)(w + 112 * MBc);
    unsigned short* qn    = (unsigned short*)(w + 112 * MBc);
    unsigned short* vv    = (unsigned short*)(w + 128 * MBc);
    unsigned short* zb    = (unsigned short*)(w + 160 * MBc);
    float* gbuf  = (float*)(w + 192 * MBc);
    float* bbuf  = (float*)(w + 192 * MBc + 512 * 1024);
    float* expG  = (float*)(w + 192 * MBc + 1024 * 1024);
    float* expGr = (float*)(w + 192 * MBc + 1536 * 1024);
    float* WabP  = (float*)(w + 194 * MBc);

    pack_ab_k<<<512, 256, 0, stream>>>(W_a, W_b, WabP);
    cast_bf16_k<<<(BT_ * DIM_ / 8 + 255) / 256, 256, 0, stream>>>(x, xb, BT_ * DIM_ / 8);
    ab_gbeta_k<<<BT_ / 4, 256, 0, stream>>>(x, WabP, dt_bias, A_log, gbuf, bbuf);
    transpose_cast_k<<<dim3(CONV_DIM_ / 32, DIM_ / 32), 256, 0, stream>>>(W_qkv, WqkvT, DIM_, CONV_DIM_);
    transpose_cast_k<<<dim3(VAL_DIM_ / 32, DIM_ / 32), 256, 0, stream>>>(W_z, WzT, DIM_, VAL_DIM_);
    gemm256_bt_k<1><<<dim3(CONV_DIM_ / 256, BT_ / 256), 512, 131072, stream>>>(xb, WqkvT, mixp, BT_, CONV_DIM_, DIM_);
    gemm256_bt_k<1><<<dim3(VAL_DIM_ / 256, BT_ / 256), 512, 131072, stream>>>(xb, WzT, zb, BT_, VAL_DIM_, DIM_);
    transpose_cast_k<<<dim3(DIM_ / 32, VAL_DIM_ / 32), 256, 0, stream>>>(W_out, WoutT, VAL_DIM_, DIM_);
    conv_fused_k<<<dim3(BT_ / 4, CONV_DIM_ / 512), 256, 0, stream>>>(mixp, conv_w, qn, kn, vv);
    chunk_pre_k<<<dim3(NC_, HV_ / 2, B_), 256, 0, stream>>>(qn, kn, vv, gbuf, bbuf,
                                                            Wmat, Aog, knT, expG, expGr);
    chunk_scan_k<<<B_ * HV_ * 4, 256, 0, stream>>>(qn, knT, vv, Wmat, Aog, expG, expGr, obuf);
    norm_gate_k<<<BT_ * HV_ / 4, 256, 0, stream>>>(obuf, zb, norm_w);
    gemm256_bt_k<0><<<dim3(DIM_ / 256, BT_ / 256), 512, 131072, stream>>>(obuf, WoutT, d_out, BT_, DIM_, VAL_DIM_);
}

// Round 17
// 634.264 us; speedup vs baseline: 1.0797x; 1.0199x over previous
//
#include <hip/hip_runtime.h>
#include <hip/hip_bf16.h>
#include <cstdint>
#include <cstddef>

#define DIM_ 2048
#define HV_ 32
#define HK_ 16
#define DK_ 128
#define DV_ 128
#define KW_ 4
#define KEY_DIM_ 2048
#define VAL_DIM_ 4096
#define CONV_DIM_ 8192
#define B_ 2
#define T_ 2048
#define BT_ 4096
#define CH_ 64
#define NC_ (T_ / CH_)

typedef short s8v __attribute__((ext_vector_type(8)));
typedef float f4v __attribute__((ext_vector_type(4)));

__device__ __forceinline__ unsigned short f2b(float f) {
    union { float f; unsigned u; } c; c.f = f;
    unsigned u = c.u;
    return (unsigned short)((u + 0x7fffu + ((u >> 16) & 1u)) >> 16);
}
__device__ __forceinline__ float b2f(unsigned short s) {
    union { unsigned u; float f; } c; c.u = ((unsigned)s) << 16;
    return c.f;
}
__device__ __forceinline__ unsigned int pk2(float a, float b) {
    return (unsigned)f2b(a) | ((unsigned)f2b(b) << 16);
}
__device__ __forceinline__ float silu(float x) { return x / (1.f + expf(-x)); }

// ---------------- cast f32 -> bf16 ----------------
__global__ void cast_bf16_k(const float* __restrict__ in, unsigned short* __restrict__ out, int n8) {
    int i = blockIdx.x * blockDim.x + threadIdx.x;
    if (i >= n8) return;
    int base = i * 8;
    f4v a = *(const f4v*)(in + base);
    f4v b = *(const f4v*)(in + base + 4);
    s8v o;
    o[0] = (short)f2b(a[0]); o[1] = (short)f2b(a[1]); o[2] = (short)f2b(a[2]); o[3] = (short)f2b(a[3]);
    o[4] = (short)f2b(b[0]); o[5] = (short)f2b(b[1]); o[6] = (short)f2b(b[2]); o[7] = (short)f2b(b[3]);
    *(s8v*)(out + base) = o;
}

// ---------------- transpose + cast ----------------
__global__ void transpose_cast_k(const float* __restrict__ in, unsigned short* __restrict__ out,
                                 int R, int C) {
    __shared__ float tile[32][33];
    int c0 = blockIdx.x * 32, r0 = blockIdx.y * 32;
    int tx = threadIdx.x & 31, ty = threadIdx.x >> 5;
#pragma unroll
    for (int j = 0; j < 32; j += 8)
        tile[ty + j][tx] = in[(size_t)(r0 + ty + j) * C + c0 + tx];
    __syncthreads();
#pragma unroll
    for (int j = 0; j < 32; j += 8)
        out[(size_t)(c0 + ty + j) * R + r0 + tx] = f2b(tile[tx][ty + j]);
}

// ---------------- pack W_a||W_b -> WabP[512][64][4] f32 ----------------
__global__ void pack_ab_k(const float* __restrict__ Wa, const float* __restrict__ Wb,
                          float* __restrict__ WabP) {
    int idx = blockIdx.x * 256 + threadIdx.x;
    int k = idx >> 6;
    int c = idx & 63;
    float v = (c < 32) ? Wa[(size_t)k * 32 + c] : Wb[(size_t)k * 32 + (c - 32)];
    WabP[((size_t)(k >> 2) * 64 + c) * 4 + (k & 3)] = v;
}

// ================ 256x256 8-phase bf16 GEMM (m201 template; R17: 5 barriers/tile) ================
// R17: removed the leading barriers of phases 2/3/4. Audit: any wave past phase p's
// closing barrier knows all waves' phase-p ds_reads completed (each waited lgkmcnt(0)
// before its MFMA, MFMA before the closing barrier), and every stage() issued in
// phase p+1 writes a region last READ in a phase already closed:
//   stage(0,u+2): A-even, last read phase 1 (closed by Y1);
//   stage(1,u+2): B-even, last read phase 1 (Y1);
//   stage(2,u+2): B-odd,  last read phase 2 (Y2).
// Phase 4 has no ds_reads (bfE in registers). Closing barriers Y1-Y4 + the counted
// vmcnt protocol (writes-landed fence at Y4) are unchanged.
template <int OUT_BF16>
__global__ __launch_bounds__(512) void gemm256_bt_k(const unsigned short* __restrict__ A,
                                                    const unsigned short* __restrict__ BT,
                                                    void* __restrict__ Cv,
                                                    int M, int N, int K) {
    extern __shared__ char lds[];   // 131072 B
    const int tid = threadIdx.x;
    const int wid = tid >> 6, lane = tid & 63;
    const int wm = wid >> 2, wn = wid & 3;
    const int r15 = lane & 15, g4 = lane >> 4;
    const int m0 = blockIdx.y * 256, n0 = blockIdx.x * 256;
    const int NT = K >> 6;

    f4v acc[8][4];
#pragma unroll
    for (int i = 0; i < 8; i++)
#pragma unroll
        for (int j = 0; j < 4; j++) acc[i][j] = (f4v){0.f, 0.f, 0.f, 0.f};

    const int i8 = lane >> 3;
    const int colb = (lane & 7) << 4;

    auto stage = [&](int unit, int t) {
        int buf = t & 1;
        int matB = (unit == 1 || unit == 2);
        int rs0;
        if (unit == 0)      rs0 = wid * 8;
        else if (unit == 3) rs0 = 64 + wid * 8;
        else                rs0 = (wid < 4 ? wid * 8 : 64 + (wid - 4) * 8) + (unit == 2 ? 32 : 0);
#pragma unroll
        for (int p = 0; p < 2; p++) {
            int rowst = rs0 + p * 128;
            int row = rowst + i8;
            int scol = colb ^ ((row & 7) << 4);
            const unsigned short* g = (matB ? BT + (size_t)(n0 + row) * K
                                            : A  + (size_t)(m0 + row) * K)
                                      + t * 64 + (scol >> 1);
            char* l = lds + buf * 65536 + matB * 32768 + rowst * 128;
            __builtin_amdgcn_global_load_lds(
                (const __attribute__((address_space(1))) unsigned int*)g,
                (__attribute__((address_space(3))) unsigned int*)l, 16, 0, 0);
        }
    };
    auto loadA = [&](s8v* af, int mh, int buf) {
        char* base = lds + buf * 65536;
#pragma unroll
        for (int mi = 0; mi < 4; mi++) {
            int row = wm * 128 + mh * 64 + mi * 16 + r15;
#pragma unroll
            for (int kk = 0; kk < 2; kk++) {
                int off = row * 128 + ((kk * 64 + g4 * 16) ^ ((row & 7) << 4));
                af[mi * 2 + kk] = *(const s8v*)(base + off);
            }
        }
    };
    auto loadB = [&](s8v* bf, int nh, int buf) {
        char* base = lds + buf * 65536 + 32768;
#pragma unroll
        for (int ni = 0; ni < 2; ni++) {
            int row = wn * 64 + nh * 32 + ni * 16 + r15;
#pragma unroll
            for (int kk = 0; kk < 2; kk++) {
                int off = row * 128 + ((kk * 64 + g4 * 16) ^ ((row & 7) << 4));
                bf[ni * 2 + kk] = *(const s8v*)(base + off);
            }
        }
    };
    auto mfma16 = [&](s8v* af, s8v* bf, int mh, int nh) {
#pragma unroll
        for (int mi = 0; mi < 4; mi++)
#pragma unroll
            for (int ni = 0; ni < 2; ni++)
#pragma unroll
                for (int kk = 0; kk < 2; kk++)
                    acc[mh * 4 + mi][nh * 2 + ni] = __builtin_amdgcn_mfma_f32_16x16x32_bf16(
                        af[mi * 2 + kk], bf[ni * 2 + kk], acc[mh * 4 + mi][nh * 2 + ni], 0, 0, 0);
    };

    stage(0, 0); stage(1, 0); stage(2, 0); stage(3, 0);
    stage(0, 1); stage(1, 1); stage(2, 1);
    asm volatile("s_waitcnt vmcnt(6)" ::: "memory");
    __builtin_amdgcn_s_barrier();

    for (int u = 0; u < NT; u++) {
        int buf = u & 1;
        s8v afE[8], afO[8], bfE[4], bfO[4];

        // phase 1
        loadA(afE, 0, buf); loadB(bfE, 0, buf);
        if (u + 1 < NT) stage(3, u + 1);
        __builtin_amdgcn_s_barrier();                      // leading (kept: post-vmcnt alignment)
        asm volatile("s_waitcnt lgkmcnt(0)" ::: "memory");
        __builtin_amdgcn_sched_barrier(0);
        __builtin_amdgcn_s_setprio(1);
        mfma16(afE, bfE, 0, 0);
        __builtin_amdgcn_s_setprio(0);
        __builtin_amdgcn_s_barrier();                      // Y1

        // phase 2 (leading barrier removed)
        loadB(bfO, 1, buf);
        if (u + 2 < NT) stage(0, u + 2);
        asm volatile("s_waitcnt lgkmcnt(0)" ::: "memory");
        __builtin_amdgcn_sched_barrier(0);
        __builtin_amdgcn_s_setprio(1);
        mfma16(afE, bfO, 0, 1);
        __builtin_amdgcn_s_setprio(0);
        __builtin_amdgcn_s_barrier();                      // Y2

        // phase 3 (leading barrier removed)
        loadA(afO, 1, buf);
        if (u + 2 < NT) stage(1, u + 2);
        asm volatile("s_waitcnt lgkmcnt(0)" ::: "memory");
        __builtin_amdgcn_sched_barrier(0);
        __builtin_amdgcn_s_setprio(1);
        mfma16(afO, bfO, 1, 1);
        __builtin_amdgcn_s_setprio(0);
        __builtin_amdgcn_s_barrier();                      // Y3

        // phase 4 (leading barrier removed; no ds_reads)
        if (u + 2 < NT) stage(2, u + 2);
        __builtin_amdgcn_s_setprio(1);
        mfma16(afO, bfE, 1, 0);
        __builtin_amdgcn_s_setprio(0);
        if (u == NT - 2) asm volatile("s_waitcnt vmcnt(0)" ::: "memory");
        else             asm volatile("s_waitcnt vmcnt(6)" ::: "memory");
        __builtin_amdgcn_s_barrier();                      // Y4
    }

#pragma unroll
    for (int mi = 0; mi < 8; mi++)
#pragma unroll
        for (int ni = 0; ni < 4; ni++) {
            int row = m0 + wm * 128 + mi * 16 + g4 * 4;
            int col = n0 + wn * 64 + ni * 16 + r15;
#pragma unroll
            for (int r = 0; r < 4; r++) {
                float v = acc[mi][ni][r];
                if (OUT_BF16)
                    ((unsigned short*)Cv)[(size_t)(row + r) * N + col] = f2b(v);
                else
                    ((float*)Cv)[(size_t)(row + r) * N + col] = v;
            }
        }
}

// ---------------- a,b GEMM (exact f32) + g/beta ----------------
__global__ __launch_bounds__(256) void ab_gbeta_k(const float* __restrict__ x,
                                                  const float* __restrict__ WabP,
                                                  const float* __restrict__ dt_bias,
                                                  const float* __restrict__ A_log,
                                                  float* __restrict__ g, float* __restrict__ beta) {
    const int c = threadIdx.x & 63;
    const int rg = __builtin_amdgcn_readfirstlane(threadIdx.x >> 6);
    const int row = blockIdx.x * 4 + rg;
    const float* xp = x + (size_t)row * 2048;
    const float* wp = WabP + c * 4;
    float acc0 = 0.f, acc1 = 0.f;
#pragma unroll 4
    for (int kb = 0; kb < 512; kb += 2) {
        f4v w0 = *(const f4v*)(wp + (size_t)kb * 256);
        f4v w1 = *(const f4v*)(wp + (size_t)(kb + 1) * 256);
        f4v x0 = *(const f4v*)(xp + kb * 4);
        f4v x1 = *(const f4v*)(xp + kb * 4 + 4);
        acc0 += x0[0] * w0[0] + x0[1] * w0[1] + x0[2] * w0[2] + x0[3] * w0[3];
        acc1 += x1[0] * w1[0] + x1[1] * w1[1] + x1[2] * w1[2] + x1[3] * w1[3];
    }
    float tot = acc0 + acc1;
    if (c < 32) {
        float av = tot + dt_bias[c];
        float sp = (av > 20.f) ? av : log1pf(expf(av));
        g[(size_t)row * 32 + c] = -expf(A_log[c]) * sp;
    } else {
        beta[(size_t)row * 32 + (c - 32)] = 1.f / (1.f + expf(-tot));
    }
}

// ---------------- conv + silu + l2norm + split: 4 timesteps/thread ----------------
__global__ __launch_bounds__(256) void conv_fused_k(const unsigned short* __restrict__ mixp,
                                                    const float* __restrict__ convw,
                                                    unsigned short* __restrict__ qn,
                                                    unsigned short* __restrict__ kn,
                                                    unsigned short* __restrict__ vv) {
    int btid0 = blockIdx.x * 4;
    int seqt0 = btid0 & (T_ - 1);
    int c = (blockIdx.y << 9) + (threadIdx.x << 1);
    const unsigned short* base = mixp + (size_t)btid0 * CONV_DIM_ + c;
    unsigned u[7];
#pragma unroll
    for (int j = 0; j < 7; j++)
        u[j] = (seqt0 + j >= 3) ? *(const unsigned*)(base + (ptrdiff_t)(j - 3) * CONV_DIM_) : 0u;
    f4v w0 = *(const f4v*)(convw + (size_t)c * 4);
    f4v w1 = *(const f4v*)(convw + (size_t)c * 4 + 4);
    float v0[4], v1[4];
#pragma unroll
    for (int tt = 0; tt < 4; tt++) {
        float a0 = 0.f, a1 = 0.f;
#pragma unroll
        for (int tau = 0; tau < 4; tau++) {
            unsigned m = u[tt + tau];
            a0 += b2f((unsigned short)(m & 0xffff)) * w0[tau];
            a1 += b2f((unsigned short)(m >> 16)) * w1[tau];
        }
        v0[tt] = silu(a0); v1[tt] = silu(a1);
    }
    if (c < 2 * KEY_DIM_) {
        int head = (c >> 7) & 15, d = c & 127;
        bool isq = c < KEY_DIM_;
        unsigned short* dst = isq ? qn : kn;
#pragma unroll
        for (int tt = 0; tt < 4; tt++) {
            float ss = v0[tt] * v0[tt] + v1[tt] * v1[tt];
#pragma unroll
            for (int m = 1; m < 64; m <<= 1) ss += __shfl_xor(ss, m);
            float scale = rsqrtf(ss + 1e-6f);
            if (isq) scale *= 0.08838834764831845f;
            *(unsigned*)(dst + ((size_t)(btid0 + tt) * HK_ + head) * DK_ + d) = pk2(v0[tt] * scale, v1[tt] * scale);
        }
    } else {
#pragma unroll
        for (int tt = 0; tt < 4; tt++)
            *(unsigned*)(vv + (size_t)(btid0 + tt) * VAL_DIM_ + (c - 2 * KEY_DIM_)) = pk2(v0[tt], v1[tt]);
    }
}

// ================= chunked delta rule: parallel precompute (h-pair merged; R12 trisolve) =================
__global__ __launch_bounds__(256) void chunk_pre_k(
    const unsigned short* __restrict__ qn, const unsigned short* __restrict__ kn,
    unsigned short* __restrict__ vv,
    const float* __restrict__ g, const float* __restrict__ beta,
    unsigned short* __restrict__ Wg, unsigned short* __restrict__ Aog,
    unsigned short* __restrict__ knT, float* __restrict__ expG, float* __restrict__ expGr)
{
    const int c = blockIdx.x, hp = blockIdx.y, b = blockIdx.z;
    const int tid = threadIdx.x, wid = tid >> 6, lane = tid & 63;
    const int r15 = lane & 15, g4 = lane >> 4;

    __shared__ __attribute__((aligned(16))) unsigned short Klds[64 * 128];
    __shared__ __attribute__((aligned(16))) unsigned short Xlds[128 * 64];
    __shared__ float AT[64][68];
    __shared__ float STmp[16][17];
    __shared__ float Gl2[2][64], Bl2[2][64], EG2[2][64];

    const size_t t0 = (size_t)b * T_ + (size_t)c * 64;

#pragma unroll
    for (int p = 0; p < 4; p++) {
        int row = p * 16 + (tid >> 4);
        int colB = (tid & 15) << 4;
        int sw = colB ^ ((row & 7) << 4);
        s8v kv = *(const s8v*)(kn + ((t0 + row) * HK_ + hp) * DK_ + (colB >> 1));
        *(s8v*)((char*)Klds + row * 256 + sw) = kv;
        s8v qv = *(const s8v*)(qn + ((t0 + row) * HK_ + hp) * DK_ + (colB >> 1));
        *(s8v*)((char*)Xlds + row * 256 + sw) = qv;
    }
    if (wid < 2) {
        int h = hp * 2 + wid;
        float v = g[(t0 + lane) * HV_ + h];
        float bv = beta[(t0 + lane) * HV_ + h];
#pragma unroll
        for (int off = 1; off < 64; off <<= 1) {
            float n = __shfl_up(v, off);
            if (lane >= off) v += n;
        }
        float Gn = __shfl(v, 63);
        float e1 = expf(v), e2 = expf(Gn - v);
        Gl2[wid][lane] = v;
        Bl2[wid][lane] = bv;
        EG2[wid][lane] = e1;
        size_t cbk = ((size_t)(b * 32 + h) * 32 + c);
        expG[cbk * 64 + lane] = e1;
        expGr[cbk * 64 + lane] = e2;
    }
    __syncthreads();

    f4v kkv[4], qkv[4];
#pragma unroll
    for (int jt = 0; jt < 4; jt++) { kkv[jt] = (f4v){0,0,0,0}; qkv[jt] = (f4v){0,0,0,0}; }
    const int arow = wid * 16 + r15;
#pragma unroll
    for (int ks = 0; ks < 4; ks++) {
        int abyte = arow * 256 + ((ks * 64 + (g4 << 4)) ^ ((arow & 7) << 4));
        s8v ak = *(const s8v*)((const char*)Klds + abyte);
        s8v aq = *(const s8v*)((const char*)Xlds + abyte);
#pragma unroll
        for (int jt = 0; jt < 4; jt++) {
            int jrow = jt * 16 + r15;
            int bbyte = jrow * 256 + ((ks * 64 + (g4 << 4)) ^ ((jrow & 7) << 4));
            s8v bk = *(const s8v*)((const char*)Klds + bbyte);
            kkv[jt] = __builtin_amdgcn_mfma_f32_16x16x32_bf16(ak, bk, kkv[jt], 0, 0, 0);
            qkv[jt] = __builtin_amdgcn_mfma_f32_16x16x32_bf16(aq, bk, qkv[jt], 0, 0, 0);
        }
    }

    for (int hh = 0; hh < 2; hh++) {
        const int h = hp * 2 + hh;
        const size_t cbk = ((size_t)(b * 32 + h) * 32 + c);

#pragma unroll
        for (int jt = 0; jt < 4; jt++) {
#pragma unroll
            for (int r = 0; r < 4; r++) {
                int i = wid * 16 + g4 * 4 + r;
                int j = jt * 16 + r15;
                float em = expf(fminf(Gl2[hh][i] - Gl2[hh][j], 0.f));
                AT[i][j] = (j < i) ? Bl2[hh][i] * em * kkv[jt][r] : 0.f;
                float ao = (j <= i) ? em * qkv[jt][r] : 0.f;
                Aog[cbk * 4096 + i * 64 + j] = f2b(ao);
            }
        }
        __syncthreads();

        for (int u = tid; u < 1024; u += 256) {
            int row = u >> 4, v0i = (u & 15) << 3;
            s8v vx = *(const s8v*)(vv + (t0 + row) * VAL_DIM_ + h * 128 + v0i);
            float bt = Bl2[hh][row];
#pragma unroll
            for (int e = 0; e < 8; e++) {
                int v = v0i + e;
                *(unsigned short*)((char*)Xlds + v * 128 + ((row * 2) ^ ((v & 7) << 4))) =
                    f2b(b2f((unsigned short)vx[e]) * bt);
            }
        }
        if (hh == 0) {
            int dk = tid & 127, th = (tid >> 7) << 5;
            size_t basek = ((size_t)(b * 16 + hp) * 128 + dk) * (size_t)T_ + (size_t)c * 64 + th;
#pragma unroll
            for (int t8 = 0; t8 < 4; t8++) {
                s8v kv;
#pragma unroll
                for (int e = 0; e < 8; e++) {
                    int tt = th + t8 * 8 + e;
                    kv[e] = (short)*(const unsigned short*)((const char*)Klds + tt * 256 + ((dk * 2) ^ ((tt & 7) << 4)));
                }
                *(s8v*)(knT + basek + t8 * 8) = kv;
            }
        }
        __syncthreads();

        if (lane < 16) {
            int r0 = wid * 16, col = lane;
#pragma unroll
            for (int i = 0; i < 16; i++) {
                float s = 0.f;
                for (int j = 0; j < i; j++) s += AT[r0 + i][r0 + j] * AT[r0 + j][r0 + col];
                AT[r0 + i][r0 + col] = ((col == i) ? 1.f : 0.f) - s;
            }
        }
        __syncthreads();

        {
            int ii = tid >> 4, jj = tid & 15;
            for (int I = 1; I < 4; I++)
                for (int J = 0; J < I; J++) {
                    float s = 0.f;
                    for (int K = J; K < I; K++) {
#pragma unroll
                        for (int m = 0; m < 16; m++)
                            s += AT[16 * I + ii][16 * K + m] * AT[16 * K + m][16 * J + jj];
                    }
                    STmp[ii][jj] = s;
                    __syncthreads();
                    float y = 0.f;
#pragma unroll
                    for (int m = 0; m < 16; m++) y += AT[16 * I + ii][16 * I + m] * STmp[m][jj];
                    __syncthreads();
                    AT[16 * I + ii][16 * J + jj] = -y;
                    __syncthreads();
                }
        }

        f4v tb[8];
#pragma unroll
        for (int vt = 0; vt < 8; vt++) tb[vt] = (f4v){0,0,0,0};
#pragma unroll
        for (int ks = 0; ks < 2; ks++) {
            s8v ta;
#pragma unroll
            for (int e = 0; e < 8; e++) ta[e] = (short)f2b(AT[arow][ks * 32 + g4 * 8 + e]);
#pragma unroll
            for (int vt = 0; vt < 8; vt++) {
                int v = vt * 16 + r15;
                int bbyte = v * 128 + ((ks * 64 + (g4 << 4)) ^ ((v & 7) << 4));
                s8v bv = *(const s8v*)((const char*)Xlds + bbyte);
                tb[vt] = __builtin_amdgcn_mfma_f32_16x16x32_bf16(ta, bv, tb[vt], 0, 0, 0);
            }
        }
#pragma unroll
        for (int vt = 0; vt < 8; vt++)
#pragma unroll
            for (int r = 0; r < 4; r++) {
                int i = wid * 16 + g4 * 4 + r, v = vt * 16 + r15;
                vv[(t0 + i) * VAL_DIM_ + h * 128 + v] = f2b(tb[vt][r]);
            }
        __syncthreads();

        {
            int dk = tid & 127;
            int tb0 = (tid >> 7) << 5;
#pragma unroll
            for (int t8 = 0; t8 < 4; t8++) {
                int tbase = tb0 + t8 * 8;
                s8v kw;
#pragma unroll
                for (int e = 0; e < 8; e++) {
                    int t = tbase + e;
                    float kv = b2f(*(const unsigned short*)((const char*)Klds + t * 256 + ((dk * 2) ^ ((t & 7) << 4))));
                    kw[e] = (short)f2b(kv * Bl2[hh][t] * EG2[hh][t]);
                }
                *(s8v*)((char*)Xlds + dk * 128 + ((tbase * 2) ^ ((dk & 7) << 4))) = kw;
            }
        }
        __syncthreads();

        f4v wm[8];
#pragma unroll
        for (int dt = 0; dt < 8; dt++) wm[dt] = (f4v){0,0,0,0};
#pragma unroll
        for (int ks = 0; ks < 2; ks++) {
            s8v ta;
#pragma unroll
            for (int e = 0; e < 8; e++) ta[e] = (short)f2b(AT[arow][ks * 32 + g4 * 8 + e]);
#pragma unroll
            for (int dt = 0; dt < 8; dt++) {
                int dkr = dt * 16 + r15;
                int bbyte = dkr * 128 + ((ks * 64 + (g4 << 4)) ^ ((dkr & 7) << 4));
                s8v bw = *(const s8v*)((const char*)Xlds + bbyte);
                wm[dt] = __builtin_amdgcn_mfma_f32_16x16x32_bf16(ta, bw, wm[dt], 0, 0, 0);
            }
        }
#pragma unroll
        for (int dt = 0; dt < 8; dt++)
#pragma unroll
            for (int r = 0; r < 4; r++) {
                int i = wid * 16 + g4 * 4 + r, dk = dt * 16 + r15;
                Wg[cbk * 8192 + i * 128 + dk] = f2b(wm[dt][r]);
            }
        __syncthreads();
    }
}

// ================= chunked delta rule: sequential scan =================
__global__ __launch_bounds__(256) void chunk_scan_k(
    const unsigned short* __restrict__ qn, const unsigned short* __restrict__ knT,
    const unsigned short* __restrict__ tbv,
    const unsigned short* __restrict__ Wg, const unsigned short* __restrict__ Aog,
    const float* __restrict__ expG, const float* __restrict__ expGr,
    unsigned short* __restrict__ ob)
{
    const int bx = blockIdx.x;
    const int vq = bx & 3, h = (bx >> 2) & 31, b = bx >> 7;
    const int hk = h >> 1;
    const int tid = threadIdx.x, wid = tid >> 6, lane = tid & 63;
    const int r15 = lane & 15, g4 = lane >> 4;

    __shared__ __attribute__((aligned(16))) unsigned short Slds[32 * 128];
    __shared__ __attribute__((aligned(16))) unsigned short Ulds[32 * 64];
    __shared__ __attribute__((aligned(16))) unsigned short Uplds[32 * 64];

    f4v S[2][2];
#pragma unroll
    for (int i = 0; i < 2; i++)
#pragma unroll
        for (int j = 0; j < 2; j++) S[i][j] = (f4v){0,0,0,0};

    struct ScanOps {
        s8v aw[4], aa[2], ak[4], q0[4];
        float tv[8], egr4[4], egi, gam;
    };
    ScanOps opA, opB;

    const unsigned short* kpbase = knT + ((size_t)(b * 16 + hk) * 128) * (size_t)T_;

    auto scan_load = [&](ScanOps& o, int c) {
        const size_t cbk = ((size_t)(b * 32 + h) * 32 + c);
        const size_t t0 = (size_t)b * T_ + (size_t)c * 64;
        const unsigned short* wp = Wg + cbk * 8192 + (size_t)(wid * 16 + r15) * 128;
#pragma unroll
        for (int ks = 0; ks < 4; ks++) o.aw[ks] = *(const s8v*)(wp + ks * 32 + g4 * 8);
        const unsigned short* ap = Aog + cbk * 4096 + (size_t)(wid * 16 + r15) * 64;
#pragma unroll
        for (int ks = 0; ks < 2; ks++) o.aa[ks] = *(const s8v*)(ap + ks * 32 + g4 * 8);
#pragma unroll
        for (int ks = 0; ks < 2; ks++)
#pragma unroll
            for (int dkt = 0; dkt < 2; dkt++)
                o.ak[ks * 2 + dkt] = *(const s8v*)(kpbase +
                    (size_t)((wid * 2 + dkt) * 16 + r15) * T_ + (size_t)c * 64 + ks * 32 + g4 * 8);
        const unsigned short* qp = qn + ((t0 + wid * 16 + r15) * HK_ + hk) * DK_;
#pragma unroll
        for (int ks = 0; ks < 4; ks++) o.q0[ks] = *(const s8v*)(qp + ks * 32 + g4 * 8);
#pragma unroll
        for (int vt = 0; vt < 2; vt++)
#pragma unroll
            for (int r = 0; r < 4; r++) {
                int t = wid * 16 + g4 * 4 + r;
                o.tv[vt * 4 + r] = b2f(tbv[(t0 + t) * VAL_DIM_ + h * 128 + vq * 32 + vt * 16 + r15]);
            }
#pragma unroll
        for (int r = 0; r < 4; r++) o.egr4[r] = expGr[cbk * 64 + wid * 16 + g4 * 4 + r];
        o.egi = expG[cbk * 64 + wid * 16 + r15];
        o.gam = expG[cbk * 64 + 63];
    };

    auto body = [&](ScanOps& o, int c) {
#pragma unroll
        for (int dkt = 0; dkt < 2; dkt++)
#pragma unroll
            for (int vt = 0; vt < 2; vt++) {
                int v = vt * 16 + r15;
                int dkb = ((wid * 2 + dkt) * 16 + g4 * 4) * 2;
                int sw = (v & 7) << 4;
                *(unsigned int*)((char*)Slds + v * 256 + ((dkb) ^ sw))     = pk2(S[dkt][vt][0], S[dkt][vt][1]);
                *(unsigned int*)((char*)Slds + v * 256 + ((dkb + 4) ^ sw)) = pk2(S[dkt][vt][2], S[dkt][vt][3]);
            }
        __syncthreads();

        f4v P[2]; P[0] = (f4v){0,0,0,0}; P[1] = (f4v){0,0,0,0};
        s8v sf[4][2];
#pragma unroll
        for (int ks = 0; ks < 4; ks++)
#pragma unroll
            for (int vt = 0; vt < 2; vt++) {
                int v = vt * 16 + r15;
                sf[ks][vt] = *(const s8v*)((const char*)Slds + v * 256 + ((ks * 64 + g4 * 16) ^ ((v & 7) << 4)));
                P[vt] = __builtin_amdgcn_mfma_f32_16x16x32_bf16(o.aw[ks], sf[ks][vt], P[vt], 0, 0, 0);
            }
#pragma unroll
        for (int vt = 0; vt < 2; vt++) {
            float uu[4], up[4];
#pragma unroll
            for (int r = 0; r < 4; r++) {
                uu[r] = o.tv[vt * 4 + r] - P[vt][r];
                up[r] = uu[r] * o.egr4[r];
            }
            int v = vt * 16 + r15;
            int tb2 = (wid * 16 + g4 * 4) * 2;
            int sw = (v & 7) << 4;
            *(unsigned int*)((char*)Ulds  + v * 128 + ((tb2) ^ sw))     = pk2(uu[0], uu[1]);
            *(unsigned int*)((char*)Ulds  + v * 128 + ((tb2 + 4) ^ sw)) = pk2(uu[2], uu[3]);
            *(unsigned int*)((char*)Uplds + v * 128 + ((tb2) ^ sw))     = pk2(up[0], up[1]);
            *(unsigned int*)((char*)Uplds + v * 128 + ((tb2 + 4) ^ sw)) = pk2(up[2], up[3]);
        }

        f4v O[2]; O[0] = (f4v){0,0,0,0}; O[1] = (f4v){0,0,0,0};
#pragma unroll
        for (int ks = 0; ks < 4; ks++) {
            s8v qg;
#pragma unroll
            for (int e = 0; e < 8; e++) qg[e] = (short)f2b(b2f((unsigned short)o.q0[ks][e]) * o.egi);
#pragma unroll
            for (int vt = 0; vt < 2; vt++)
                O[vt] = __builtin_amdgcn_mfma_f32_16x16x32_bf16(qg, sf[ks][vt], O[vt], 0, 0, 0);
        }
        __syncthreads();

#pragma unroll
        for (int ks = 0; ks < 2; ks++)
#pragma unroll
            for (int vt = 0; vt < 2; vt++) {
                int v = vt * 16 + r15;
                s8v bu = *(const s8v*)((const char*)Ulds + v * 128 + ((ks * 64 + g4 * 16) ^ ((v & 7) << 4)));
                O[vt] = __builtin_amdgcn_mfma_f32_16x16x32_bf16(o.aa[ks], bu, O[vt], 0, 0, 0);
            }
#pragma unroll
        for (int vt = 0; vt < 2; vt++)
#pragma unroll
            for (int r = 0; r < 4; r++) {
                int t = c * 64 + wid * 16 + g4 * 4 + r;
                ob[((size_t)b * T_ + t) * VAL_DIM_ + h * 128 + vq * 32 + vt * 16 + r15] = f2b(O[vt][r]);
            }

#pragma unroll
        for (int dkt = 0; dkt < 2; dkt++)
#pragma unroll
            for (int vt = 0; vt < 2; vt++) {
                S[dkt][vt][0] *= o.gam; S[dkt][vt][1] *= o.gam;
                S[dkt][vt][2] *= o.gam; S[dkt][vt][3] *= o.gam;
            }
#pragma unroll
        for (int ks = 0; ks < 2; ks++) {
            s8v bu[2];
#pragma unroll
            for (int vt = 0; vt < 2; vt++) {
                int v = vt * 16 + r15;
                bu[vt] = *(const s8v*)((const char*)Uplds + v * 128 + ((ks * 64 + g4 * 16) ^ ((v & 7) << 4)));
            }
#pragma unroll
            for (int dkt = 0; dkt < 2; dkt++)
#pragma unroll
                for (int vt = 0; vt < 2; vt++)
                    S[dkt][vt] = __builtin_amdgcn_mfma_f32_16x16x32_bf16(o.ak[ks * 2 + dkt], bu[vt], S[dkt][vt], 0, 0, 0);
        }
    };

    scan_load(opA, 0);
    for (int c = 0; c < NC_; c += 2) {
        scan_load(opB, (c + 1 < NC_) ? c + 1 : c);
        body(opA, c);
        if (c + 2 < NC_) scan_load(opA, c + 2);
        body(opB, c + 1);
    }
}

// ---------------- gated RMSNorm + silu(z) gate ----------------
__global__ __launch_bounds__(256) void norm_gate_k(unsigned short* __restrict__ o,
                                                   const unsigned short* __restrict__ z,
                                                   const float* __restrict__ nw) {
    int lane = threadIdx.x & 63;
    size_t bh = (size_t)blockIdx.x * 4 + (threadIdx.x >> 6);
    unsigned ov = *(unsigned*)(o + bh * 128 + lane * 2);
    float v0 = b2f((unsigned short)(ov & 0xffff)), v1 = b2f((unsigned short)(ov >> 16));
    float ss = v0 * v0 + v1 * v1;
#pragma unroll
    for (int m = 1; m < 64; m <<= 1) ss += __shfl_xor(ss, m);
    float rr = rsqrtf(ss * (1.f / 128.f) + 1e-6f);
    unsigned zv = *(const unsigned*)(z + bh * 128 + lane * 2);
    float z0 = b2f((unsigned short)(zv & 0xffff)), z1 = b2f((unsigned short)(zv >> 16));
    float o0 = v0 * rr * nw[lane * 2]     * silu(z0);
    float o1 = v1 * rr * nw[lane * 2 + 1] * silu(z1);
    *(unsigned*)(o + bh * 128 + lane * 2) = pk2(o0, o1);
}

// ---------------- launch ----------------
extern "C" void kernel_launch(void* const* d_in, const int* in_sizes, int n_in,
                              void* d_out, int out_size, void* d_ws, size_t ws_size,
                              hipStream_t stream) {
    const float* x      = (const float*)d_in[0];
    const float* W_qkv  = (const float*)d_in[1];
    const float* W_z    = (const float*)d_in[2];
    const float* W_a    = (const float*)d_in[3];
    const float* W_b    = (const float*)d_in[4];
    const float* W_out  = (const float*)d_in[5];
    const float* conv_w = (const float*)d_in[6];
    const float* dt_bias= (const float*)d_in[7];
    const float* A_log  = (const float*)d_in[8];
    const float* norm_w = (const float*)d_in[9];

    char* w = (char*)d_ws;
    const size_t MBc = (size_t)1 << 20;
    unsigned short* mixp  = (unsigned short*)(w);
    unsigned short* Wmat  = (unsigned short*)(w);
    unsigned short* knT   = (unsigned short*)(w + 32 * MBc);
    unsigned short* Aog   = (unsigned short*)(w + 48 * MBc);
    unsigned short* WqkvT = (unsigned short*)(w + 64 * MBc);
    unsigned short* obuf  = (unsigned short*)(w + 64 * MBc);
    unsigned short* kn    = (unsigned short*)(w + 80 * MBc);
    unsigned short* WzT   = (unsigned short*)(w + 96 * MBc);
    unsigned short* WoutT = (unsigned short*)(w + 96 * MBc);
    unsigned short* xb    = (unsigned short*)(w + 112 * MBc);
    unsigned short* qn    = (unsigned short*)(w + 112 * MBc);
    unsigned short* vv    = (unsigned short*)(w + 128 * MBc);
    unsigned short* zb    = (unsigned short*)(w + 160 * MBc);
    float* gbuf  = (float*)(w + 192 * MBc);
    float* bbuf  = (float*)(w + 192 * MBc + 512 * 1024);
    float* expG  = (float*)(w + 192 * MBc + 1024 * 1024);
    float* expGr = (float*)(w + 192 * MBc + 1536 * 1024);
    float* WabP  = (float*)(w + 194 * MBc);

    pack_ab_k<<<512, 256, 0, stream>>>(W_a, W_b, WabP);
    cast_bf16_k<<<(BT_ * DIM_ / 8 + 255) / 256, 256, 0, stream>>>(x, xb, BT_ * DIM_ / 8);
    ab_gbeta_k<<<BT_ / 4, 256, 0, stream>>>(x, WabP, dt_bias, A_log, gbuf, bbuf);
    transpose_cast_k<<<dim3(CONV_DIM_ / 32, DIM_ / 32), 256, 0, stream>>>(W_qkv, WqkvT, DIM_, CONV_DIM_);
    transpose_cast_k<<<dim3(VAL_DIM_ / 32, DIM_ / 32), 256, 0, stream>>>(W_z, WzT, DIM_, VAL_DIM_);
    gemm256_bt_k<1><<<dim3(CONV_DIM_ / 256, BT_ / 256), 512, 131072, stream>>>(xb, WqkvT, mixp, BT_, CONV_DIM_, DIM_);
    gemm256_bt_k<1><<<dim3(VAL_DIM_ / 256, BT_ / 256), 512, 131072, stream>>>(xb, WzT, zb, BT_, VAL_DIM_, DIM_);
    transpose_cast_k<<<dim3(DIM_ / 32, VAL_DIM_ / 32), 256, 0, stream>>>(W_out, WoutT, VAL_DIM_, DIM_);
    conv_fused_k<<<dim3(BT_ / 4, CONV_DIM_ / 512), 256, 0, stream>>>(mixp, conv_w, qn, kn, vv);
    chunk_pre_k<<<dim3(NC_, HV_ / 2, B_), 256, 0, stream>>>(qn, kn, vv, gbuf, bbuf,
                                                            Wmat, Aog, knT, expG, expGr);
    chunk_scan_k<<<B_ * HV_ * 4, 256, 0, stream>>>(qn, knT, vv, Wmat, Aog, expG, expGr, obuf);
    norm_gate_k<<<BT_ * HV_ / 4, 256, 0, stream>>>(obuf, zb, norm_w);
    gemm256_bt_k<0><<<dim3(DIM_ / 256, BT_ / 256), 512, 131072, stream>>>(obuf, WoutT, d_out, BT_, DIM_, VAL_DIM_);
}